// Round 13
// baseline (3642.839 us; speedup 1.0000x reference)
//
#include <hip/hip_runtime.h>

#define B_   4
#define C_   192
#define E_   768
#define H0   64
#define H_   128
#define HW   (H_*H_)        // 16384
#define PLANE0 (H0*H0)      // 4096
#define NPIX (B_*HW)        // 65536
#define NOUT (B_*C_*HW)     // 12582912

// halo-padded pixel-major xm: [b][130][130][192] bf16, lives in d_out[0:NOUT]
#define XTW  130
#define XTPL (XTW*XTW)       // 16,900

// ws layout (bytes)
#define OFF_S    0u
#define OFF_FAC  262144u
#define OFF_MH   524288u
#define OFF_MU   786432u     // u8 3,145,728
#define OFF_M1   3932160u    // u8 12,582,912
#define OFF_WEB3 16515072u   // 108 tiles x [c8 4][e 384][8] bf16 = 2,654,208 (K-major)
#define OFF_WPB3 19169280u   // 12 chunks x [e8 8][co 192][8] bf16 = 294,912 (half/el-mapped)
#define OFF_GB   19464192u   // 192*192 bf16 = 73,728
// end 19,537,920

typedef __attribute__((ext_vector_type(8))) short bf16x8;
typedef __attribute__((ext_vector_type(4))) float f32x4;

__device__ __forceinline__ unsigned short f2bf(float f) {
    unsigned u = __float_as_uint(f);
    u += 0x7FFFu + ((u >> 16) & 1u);   // RNE
    return (unsigned short)(u >> 16);
}

__device__ __forceinline__ void gll16(const void* g, void* l) {
    __builtin_amdgcn_global_load_lds(
        (const __attribute__((address_space(1))) unsigned int*)g,
        (__attribute__((address_space(3))) unsigned int*)l, 16, 0, 0);
}

// ---------------- K0: zero halo ring of xmT ----------------
__global__ __launch_bounds__(256) void k_zhalo(short* __restrict__ xmT)
{
    int idx = blockIdx.x*256 + threadIdx.x;   // 4 * 516 * 24 = 49,536
    if (idx >= 49536) return;
    int g = idx % 24;
    int pp = (idx / 24) % 516;
    int b = idx / (24*516);
    int i, j;
    if (pp < 130)      { i = 0;   j = pp; }
    else if (pp < 260) { i = 129; j = pp - 130; }
    else { int q = pp - 260; i = 1 + (q >> 1); j = (q & 1) * 129; }
    *(bf16x8*)&xmT[((size_t)(b*XTPL + i*XTW + j))*192 + g*8] = (bf16x8)(short)0;
}

// ---------------- K1: partial IDWT + mask union (8 waves, parity-specialized) ----------------
__global__ __launch_bounds__(512) void k_idwt(
    const float* __restrict__ ll, const float* __restrict__ lh,
    const float* __restrict__ hl, const float* __restrict__ hh,
    const int* __restrict__ llm, const int* __restrict__ m1,
    const int* __restrict__ m2, const int* __restrict__ m3,
    float* __restrict__ pre, unsigned char* __restrict__ mu)
{
    const float G0c[7] = {-0.091271763114f,-0.057543526228f,0.591271763114f,1.115087052457f,
                          0.591271763114f,-0.057543526228f,-0.091271763114f};
    const float G1c[9] = {0.026748757411f,0.016864118443f,-0.078223266529f,-0.266864118443f,
                          0.602949018236f,-0.266864118443f,-0.078223266529f,0.016864118443f,
                          0.026748757411f};
    __shared__ float lo[H_*H0];
    __shared__ float hi[H_*H0];
    const int bc = blockIdx.x;
    const int base = bc * PLANE0;
    const int t = threadIdx.x;
    const int w = t >> 6, lane = t & 63;

    #pragma unroll 1
    for (int iter = 0; iter < 16; ++iter) {
        const int o = iter*8 + w;
        float alo = 0.f, ahi = 0.f;
        if (o & 1) {
            #pragma unroll
            for (int s = 0; s < 4; ++s) {
                int d = o - 3 + 2*s;
                if ((unsigned)d <= 126u) {
                    int q = base + (d >> 1)*H0 + lane;
                    float g0 = G0c[2*s], g1 = G1c[2*s + 1];
                    alo += g0 * ll[q]*(float)llm[q] + g1 * lh[q]*(float)m1[q];
                    ahi += g0 * hl[q]*(float)m2[q] + g1 * hh[q]*(float)m3[q];
                }
            }
        } else {
            #pragma unroll
            for (int s = 0; s < 5; ++s) {
                int d = o - 4 + 2*s;
                if ((unsigned)d <= 126u) {
                    int q = base + (d >> 1)*H0 + lane;
                    float g1 = G1c[2*s];
                    alo += g1 * lh[q]*(float)m1[q];
                    ahi += g1 * hh[q]*(float)m3[q];
                    if (s >= 1 && s <= 3) {
                        float g0 = G0c[2*s - 1];
                        alo += g0 * ll[q]*(float)llm[q];
                        ahi += g0 * hl[q]*(float)m2[q];
                    }
                }
            }
        }
        lo[o*H0 + lane] = alo;
        hi[o*H0 + lane] = ahi;
    }
    for (int idx = t; idx < PLANE0; idx += 512) {
        int q = base + idx;
        mu[q] = (unsigned char)((llm[q] | m1[q] | m2[q] | m3[q]) ? 1 : 0);
    }
    __syncthreads();

    const size_t ob = (size_t)bc * HW;
    const int c = lane;
    #pragma unroll 1
    for (int iter = 0; iter < 16; ++iter) {
        const int o = iter*8 + w;
        const float* lr = lo + o*H0;
        const float* hr = hi + o*H0;
        float lC  = lr[c];
        float hC  = hr[c];
        float lM1 = (c >= 1)  ? lr[c-1] : 0.f;
        float lP1 = (c <= 62) ? lr[c+1] : 0.f;
        float lP2 = (c <= 61) ? lr[c+2] : 0.f;
        float hM2 = (c >= 2)  ? hr[c-2] : 0.f;
        float hM1 = (c >= 1)  ? hr[c-1] : 0.f;
        float hP1 = (c <= 62) ? hr[c+1] : 0.f;
        float hP2 = (c <= 61) ? hr[c+2] : 0.f;
        float pe = G0c[1]*lM1 + G0c[3]*lC + G0c[5]*lP1
                 + G1c[0]*hM2 + G1c[2]*hM1 + G1c[4]*hC + G1c[6]*hP1 + G1c[8]*hP2;
        float po = G0c[0]*lM1 + G0c[2]*lC + G0c[4]*lP1 + G0c[6]*lP2
                 + G1c[1]*hM1 + G1c[3]*hC + G1c[5]*hP1 + G1c[7]*hP2;
        float2 pv = {pe, po};
        *(float2*)&pre[ob + (size_t)o*H_ + 2*c] = pv;
    }
}

// ---------------- K2: depthwise 3x3 partial conv (cast), LDS-tiled ----------------
__global__ __launch_bounds__(256) void k_cast(
    const float* __restrict__ pre, const unsigned char* __restrict__ mu,
    const float* __restrict__ wc, const float* __restrict__ bcast,
    float* __restrict__ xm, unsigned char* __restrict__ m1out)
{
    __shared__ float sp[18*131];
    __shared__ float smv[10*66];
    const int blk = blockIdx.x;          // 6144 = 768 bc x 8 row-tiles
    const int bc = blk >> 3;
    const int i0 = (blk & 7) * 16;
    const int c = bc % C_;
    const int t = threadIdx.x;
    const size_t pb = (size_t)bc * HW;
    const size_t mb = (size_t)bc * PLANE0;
    for (int q = t; q < 2340; q += 256) {
        int rr = q / 130, cc = q - rr*130;
        int gi = i0 + rr - 1, gj = cc - 1;
        float v = 0.f;
        if ((unsigned)gi < 128u && (unsigned)gj < 128u) v = pre[pb + gi*128 + gj];
        sp[rr*131 + cc] = v;
    }
    for (int q = t; q < 660; q += 256) {
        int rr = q / 66, cc = q - rr*66;
        int mi = (i0 >> 1) + rr - 1, mj = cc - 1;
        float v = 0.f;
        if ((unsigned)mi < 64u && (unsigned)mj < 64u) v = (float)mu[mb + mi*64 + mj];
        smv[rr*66 + cc] = v;
    }
    __syncthreads();
    float w9[9];
    #pragma unroll
    for (int k = 0; k < 9; ++k) w9[k] = wc[c*9 + k];
    const float bcc = bcast[c];
    const int rr = t >> 4, c8 = (t & 15) * 8;
    float ox[8]; unsigned mo = 0, mo2 = 0;
    #pragma unroll
    for (int u = 0; u < 8; ++u) {
        int j = c8 + u;
        float o = 0.f, s = 0.f;
        #pragma unroll
        for (int di = 0; di < 3; ++di) {
            int gi = i0 + rr + di - 1;
            int mrow = (gi >> 1) - (i0 >> 1) + 1;
            #pragma unroll
            for (int dj = 0; dj < 3; ++dj) {
                int gj = j + dj - 1;
                float m0v = smv[mrow*66 + (gj >> 1) + 1];
                s += m0v;
                o += m0v * sp[(rr+di)*131 + j + dj] * w9[di*3 + dj];
            }
        }
        bool valid = s > 0.f;
        ox[u] = valid ? (o * (9.f / s) + bcc) : 0.f;
        unsigned bit = valid ? 1u : 0u;
        if (u < 4) mo |= bit << (8*u); else mo2 |= bit << (8*(u-4));
    }
    size_t oidx = pb + (size_t)(i0 + rr)*128 + c8;
    f32x4 v0 = {ox[0], ox[1], ox[2], ox[3]};
    f32x4 v1 = {ox[4], ox[5], ox[6], ox[7]};
    *(f32x4*)&xm[oidx] = v0;
    *(f32x4*)&xm[oidx + 4] = v1;
    *(unsigned*)&m1out[oidx] = mo;
    *(unsigned*)&m1out[oidx + 4] = mo2;
}

// ---------------- K3: channel-sum of mask1 ----------------
__global__ __launch_bounds__(256) void k_rowsum(const unsigned char* __restrict__ m1,
                                                float* __restrict__ S)
{
    __shared__ float red[128];
    int bi = blockIdx.x;                // b*128 + i
    int b = bi >> 7, i = bi & 127;
    int t = threadIdx.x;
    int j = t & 127, half = t >> 7;
    float s = 0.f;
    size_t base = (size_t)b*C_*HW + (size_t)(half*96)*HW + (size_t)i*H_ + j;
    for (int c = 0; c < 96; ++c) s += (float)m1[base + (size_t)c*HW];
    if (half) red[j] = s;
    __syncthreads();
    if (!half) S[bi*H_ + j] = s + red[j];
}

// ---------------- K4: window-sum -> expand factor & mh ----------------
__global__ __launch_bounds__(256) void k_facm(const float* __restrict__ S,
                                              float* __restrict__ fac, float* __restrict__ mh)
{
    int px = blockIdx.x*256 + threadIdx.x;
    if (px >= NPIX) return;
    int j = px & 127, i = (px >> 7) & 127, b = px >> 14;
    float w3 = 0.f;
    #pragma unroll
    for (int di = -1; di <= 1; ++di) {
        int gi = i + di; if ((unsigned)gi >= (unsigned)H_) continue;
        #pragma unroll
        for (int dj = -1; dj <= 1; ++dj) {
            int gj = j + dj; if ((unsigned)gj >= (unsigned)H_) continue;
            w3 += S[(b*H_ + gi)*H_ + gj];
        }
    }
    bool v = w3 > 0.f;
    fac[px] = v ? 1728.f / w3 : 0.f;
    mh[px]  = v ? 1.f : 0.f;
}

// ---------------- K4b: weight convert + permute (K-major) ----------------
// web3: tile = p*54 + sc*9 + r, layout [c8 4][e 384][j 8]:
//   value = we[(p*384+e)*1728 + (sc*32 + c8*8 + j)*9 + r]
// wpb3: chunk = p*6 + h*3 + c3, layout [e8 8][co 192][8]; el = c3*64 + e8*8 + j;
//   e = p*384 + (el/48)*96 + h*48 + (el%48);  value = wp[co*768 + e]
// gb  : gamma bf16 [co][c]
__global__ __launch_bounds__(256) void k_wcvt(const float* __restrict__ we,
                                              const float* __restrict__ wp,
                                              const float* __restrict__ gamma,
                                              short* __restrict__ web3,
                                              short* __restrict__ wpb3,
                                              short* __restrict__ gb)
{
    int idx = blockIdx.x*256 + threadIdx.x;
    const int N1 = 108*12288;        // 1,327,104
    const int N2 = 12*12288;         // 147,456
    if (idx < N1) {
        int tile = idx / 12288, rem = idx % 12288;
        int g = rem >> 3, j = rem & 7;
        int c8 = g / 384, e = g % 384;
        int p = tile / 54, sc = (tile % 54) / 9, r = tile % 9;
        web3[idx] = (short)f2bf(we[(size_t)(p*384 + e)*1728 + (sc*32 + c8*8 + j)*9 + r]);
    } else if (idx < N1 + N2) {
        int i2 = idx - N1;
        int chunk = i2 / 12288, rem = i2 % 12288;
        int g = rem >> 3, j = rem & 7;
        int e8 = g / 192, co = g % 192;
        int p = chunk / 6, hf = (chunk % 6) / 3, c3 = chunk % 3;
        int el = c3*64 + e8*8 + j;
        int e = p*384 + (el/48)*96 + hf*48 + (el%48);
        wpb3[i2] = (short)f2bf(wp[(size_t)co*E_ + e]);
    } else {
        int i3 = idx - N1 - N2;
        if (i3 < C_*C_) gb[i3] = (short)f2bf(gamma[i3]);
    }
}

// ---------------- K4c: xm f32 [c][pix] -> xmT bf16 [b][130][130][192] (interior) ----------------
__global__ __launch_bounds__(256) void k_xmt(const float* __restrict__ xm,
                                             short* __restrict__ xmT)
{
    __shared__ float sm[64*65];
    const int gx = blockIdx.x;           // 3072 = 3 cb * 1024 pb
    const int cb = gx >> 10, pb = gx & 1023;
    const int c0 = cb*64, pix0 = pb*64;
    const int b = pix0 >> 14, pixb = pix0 & 16383;
    const int t = threadIdx.x;
    const int lane6 = t & 63, hi4 = t >> 6;
    #pragma unroll
    for (int it = 0; it < 16; ++it) {
        int r4 = it*4 + hi4;
        sm[r4*65 + lane6] = xm[((size_t)(b*C_ + c0 + r4))*HW + pixb + lane6];
    }
    __syncthreads();
    #pragma unroll
    for (int it = 0; it < 2; ++it) {
        int q = it*256 + t;
        int pp = q >> 3, c8 = q & 7;
        int p = pixb + pp;
        int i = p >> 7, j = p & 127;
        bf16x8 v;
        #pragma unroll
        for (int jj = 0; jj < 8; ++jj) v[jj] = (short)f2bf(sm[(c8*8+jj)*65 + pp]);
        *(bf16x8*)&xmT[((size_t)(b*XTPL + (i+1)*XTW + (j+1)))*192 + c0 + c8*8] = v;
    }
}

// ---------------- K5: MFMA fused MBConv — 74KB LDS, 2 blocks/CU ----------------
// 512 blocks x 512 thr. 2 e-passes of 384; 54 taps/pass; 2-buffer B (issue-after-drain);
// single junk-padded apat (uniform 2-gll); silu/proj in 2 halves of 192e; hB row-pad 1032.
__global__ __launch_bounds__(512, 4) void k_mbconv(
    const short* __restrict__ xmT, const short* __restrict__ web3,
    const short* __restrict__ wpb3, const float* __restrict__ be,
    const float* __restrict__ bp, const float* __restrict__ bcast,
    const float* __restrict__ fac, const float* __restrict__ mh,
    const unsigned char* __restrict__ m1, float* __restrict__ xmy)
{
    __shared__ __align__(16) char smem[74112];
    // expand: apat @0 [c8 4][256 pos][8] 16,384 (pos>=180 junk) | bB @16,384 [2][12288sh] 49,152 -> 65,536
    // proj:   hB @0 [el8 24][stride 1032 sh] 49,536 | wpB @49,536 [12288sh] 24,576 -> 74,112
    // epi:    fbuf @0 [192][68] f32 52,224
    short* apat = (short*)smem;
    short* bB0  = (short*)(smem + 16384);
    short* bB1  = (short*)(smem + 16384 + 24576);
    short* hB   = (short*)smem;
    short* wpB  = (short*)(smem + 49536);
    float* fbuf = (float*)smem;

    // XCD-aware swizzle: 512 blocks = 8 XCDs x 64 contiguous
    const int blk = (blockIdx.x & 7)*64 + (blockIdx.x >> 3);
    const int b = blk >> 7;                       // 4b x 16ti x 8tj
    const int ti = (blk >> 3) & 15, tj = blk & 7;
    const int i0 = ti*8, j0 = tj*16;              // tile = 8 rows x 16 cols
    const int t = threadIdx.x;
    const int w = t >> 6, l = t & 63;
    const int wm2 = w >> 2, we2 = w & 3;
    const int m0 = wm2 * 64;
    const int lo = l & 15, hi = l >> 4;

// uniform A staging: 1024 granules = 2 gll/thread; [c8 4][256]; pos>=180 reads junk (in-bounds)
#define ISSUE_A(sc_) do {                                                       \
    const int c0_ = (sc_)*32;                                                   \
    _Pragma("unroll")                                                           \
    for (int it_ = 0; it_ < 2; ++it_) {                                         \
        int q_ = it_*512 + t;                                                   \
        int c8_ = q_ >> 8, pos_ = q_ & 255;                                     \
        int rr_ = pos_/18, cc_ = pos_ - rr_*18;                                 \
        gll16(&xmT[((size_t)(b*XTPL + (i0+rr_)*XTW + (j0+cc_)))*192 + c0_       \
                   + c8_*8], &apat[q_*8]);                                      \
    }                                                                           \
} while(0)

#define ISSUE_B(tileIdx_, dst_) do {                                            \
    const size_t off_ = (size_t)(tileIdx_) * 12288;                             \
    _Pragma("unroll")                                                           \
    for (int it_ = 0; it_ < 3; ++it_) {                                         \
        int q_ = it_*512 + t;                                                   \
        gll16(&web3[off_ + q_*8], &(dst_)[q_*8]);                               \
    }                                                                           \
} while(0)

#define ISSUE_WP(chunkIdx_) do {                                                \
    const size_t off_ = (size_t)(chunkIdx_) * 12288;                            \
    _Pragma("unroll")                                                           \
    for (int it_ = 0; it_ < 3; ++it_) {                                         \
        int q_ = it_*512 + t;                                                   \
        gll16(&wpb3[off_ + q_*8], &wpB[q_*8]);                                  \
    }                                                                           \
} while(0)

#define WAITBAR(N_) do {                                                        \
    asm volatile("s_waitcnt vmcnt(" #N_ ") lgkmcnt(0)" ::: "memory");           \
    __builtin_amdgcn_s_barrier();                                               \
    __builtin_amdgcn_sched_barrier(0);                                          \
} while(0)

#define LGKMBAR() do {                                                          \
    asm volatile("s_waitcnt lgkmcnt(0)" ::: "memory");                          \
    __builtin_amdgcn_s_barrier();                                               \
    __builtin_amdgcn_sched_barrier(0);                                          \
} while(0)

    float facr[4][4];
    #pragma unroll
    for (int af = 0; af < 4; ++af)
        #pragma unroll
        for (int reg = 0; reg < 4; ++reg) {
            int px = m0 + af*16 + hi*4 + reg;
            facr[af][reg] = fac[b*HW + (i0 + (px >> 4))*128 + j0 + (px & 15)];
        }
    // per-thread invariant LDS bases (short indices)
    int aoffS[4], boffS[6], hpxS[4], wcoS[3];
    #pragma unroll
    for (int af = 0; af < 4; ++af) {
        int px = m0 + af*16 + lo;
        aoffS[af] = (hi*256 + (px >> 4)*18 + (px & 15)) * 8;
        hpxS[af]  = px * 8;
    }
    #pragma unroll
    for (int nf = 0; nf < 6; ++nf)
        boffS[nf] = (hi*384 + we2*96 + nf*16 + lo) * 8;
    #pragma unroll
    for (int nf = 0; nf < 3; ++nf)
        wcoS[nf] = (we2*48 + nf*16 + lo) * 8;
    const int hrowS = hi * 1032;     // + (c3*8+ks*4)*1032 immediate
    const int wrowS = hi * 1536;     // + ks*4*1536 immediate (1536 shorts = 192co*8)

    // prologue
    ISSUE_B(0, bB0);

    #pragma unroll 1
    for (int p = 0; p < 2; ++p) {
        // ================= expand: 54 taps =================
        f32x4 acc[4][6];
        #pragma unroll
        for (int a = 0; a < 4; ++a)
            #pragma unroll
            for (int n = 0; n < 6; ++n) acc[a][n] = (f32x4){0.f,0.f,0.f,0.f};

        #pragma unroll 1
        for (int sc = 0; sc < 6; ++sc) {
            const int tbase = p*54 + sc*9;
            const int scp = sc & 1;
            #pragma unroll
            for (int r = 0; r < 9; ++r) {
                const int rv = (r/3)*18 + (r%3);            // compile-time
                short* bcur = ((scp ^ (r & 1)) ? bB1 : bB0);
                short* bnxt = ((scp ^ (r & 1)) ? bB0 : bB1);
                if (r == 0) {
                    WAITBAR(0);                 // B(tile) landed; apat reads done
                    ISSUE_A(sc);
                    ISSUE_B(tbase + 1, bnxt);
                    asm volatile("s_waitcnt vmcnt(3) lgkmcnt(0)" ::: "memory");
                    __builtin_amdgcn_s_barrier();
                    __builtin_amdgcn_sched_barrier(0);
                } else {
                    WAITBAR(0);                 // B(tile) landed; bnxt reads (r-2) done
                    if (!(sc == 5 && r == 8)) ISSUE_B(tbase + r + 1, bnxt);
                }
                bf16x8 a[4], bb[6];
                #pragma unroll
                for (int af = 0; af < 4; ++af)
                    a[af] = *(const bf16x8*)&apat[aoffS[af] + rv*8];
                #pragma unroll
                for (int nf = 0; nf < 6; ++nf)
                    bb[nf] = *(const bf16x8*)&bcur[boffS[nf]];
                __builtin_amdgcn_s_setprio(1);
                #pragma unroll
                for (int af = 0; af < 4; ++af)
                    #pragma unroll
                    for (int nf = 0; nf < 6; ++nf)
                        acc[af][nf] = __builtin_amdgcn_mfma_f32_16x16x32_bf16(
                            a[af], bb[nf], acc[af][nf], 0, 0, 0);
                __builtin_amdgcn_s_setprio(0);
            }
        }

        // ================= proj: 2 halves x (silu + 3 chunks of 64e) =================
        f32x4 accy[4][3];
        #pragma unroll
        for (int a = 0; a < 4; ++a)
            #pragma unroll
            for (int n = 0; n < 3; ++n) accy[a][n] = (f32x4){0.f,0.f,0.f,0.f};

        #pragma unroll 1
        for (int h = 0; h < 2; ++h) {
            LGKMBAR();      // h0: tap53 reads done (apat/bB dead); h1: h0 proj reads done
            // silu half h -> hB (rows el8 0..23, stride 1032)
            #pragma unroll
            for (int n3 = 0; n3 < 3; ++n3) {
                const int nf = h*3 + n3;
                int el = we2*48 + n3*16 + lo;
                int e_glob = we2*96 + h*48 + n3*16 + lo;
                float bev = be[p*384 + e_glob];
                int hb = (el >> 3)*1032 + (el & 7);
                #pragma unroll
                for (int af = 0; af < 4; ++af)
                    #pragma unroll
                    for (int reg = 0; reg < 4; ++reg) {
                        int px = m0 + af*16 + hi*4 + reg;
                        float fr = facr[af][reg];
                        float v = acc[af][nf][reg]*fr + bev;
                        float hv = (fr > 0.f) ? v / (1.f + __expf(-v)) : 0.f;
                        hB[hb + px*8] = (short)f2bf(hv);
                    }
            }
            #pragma unroll 1
            for (int c3 = 0; c3 < 3; ++c3) {
                if (c3 > 0) LGKMBAR();          // prev chunk reads done before wpB overwrite
                ISSUE_WP(p*6 + h*3 + c3);
                asm volatile("s_waitcnt vmcnt(0) lgkmcnt(0)" ::: "memory");
                __builtin_amdgcn_s_barrier();
                __builtin_amdgcn_sched_barrier(0);
                #pragma unroll
                for (int ks = 0; ks < 2; ++ks) {
                    bf16x8 a[4], bb[3];
                    #pragma unroll
                    for (int af = 0; af < 4; ++af)
                        a[af] = *(const bf16x8*)&hB[(c3*8 + ks*4)*1032 + hrowS + hpxS[af]];
                    #pragma unroll
                    for (int nf = 0; nf < 3; ++nf)
                        bb[nf] = *(const bf16x8*)&wpB[ks*4*1536 + wrowS + wcoS[nf]];
                    __builtin_amdgcn_s_setprio(1);
                    #pragma unroll
                    for (int af = 0; af < 4; ++af)
                        #pragma unroll
                        for (int nf = 0; nf < 3; ++nf)
                            accy[af][nf] = __builtin_amdgcn_mfma_f32_16x16x32_bf16(
                                a[af], bb[nf], accy[af][nf], 0, 0, 0);
                    __builtin_amdgcn_s_setprio(0);
                }
            }
        }

        // ================= per-pass y accumulate =================
        LGKMBAR();                         // last proj reads done; hB/wpB dead
        #pragma unroll 1
        for (int ph = 0; ph < 2; ++ph) {
            if (wm2 == ph) {
                #pragma unroll
                for (int af = 0; af < 4; ++af)
                    #pragma unroll
                    for (int nf = 0; nf < 3; ++nf) {
                        int co = we2*48 + nf*16 + lo;
                        int pxl = af*16 + hi*4;
                        *(f32x4*)&fbuf[co*68 + pxl] = accy[af][nf];
                    }
            }
            __syncthreads();
            #pragma unroll 1
            for (int it = 0; it < 6; ++it) {
                int q = it*512 + t;              // 3072 = 192co x 16 px-quads
                int co = q >> 4, px4 = (q & 15) << 2;
                int px = ph*64 + px4;
                int pi = px >> 4, pj = px & 15;
                size_t gidx = ((size_t)(b*C_ + co))*HW + (size_t)(i0+pi)*128 + j0 + pj;
                f32x4 pv = *(f32x4*)&fbuf[co*68 + px4];
                f32x4 prev = *(const f32x4*)&xmy[gidx];
                f32x4 o;
                if (p == 0) {
                    int pixg = b*HW + (i0+pi)*128 + j0 + pj;
                    f32x4 mh4 = *(const f32x4*)&mh[pixg];
                    unsigned mu4 = *(const unsigned*)&m1[gidx];
                    float bpc = bp[co], bcc = bcast[co];
                    #pragma unroll
                    for (int k = 0; k < 4; ++k)
                        o[k] = pv[k] + bpc + prev[k] + bcc*(mh4[k] - (float)((mu4 >> (8*k)) & 255u));
                } else {
                    #pragma unroll
                    for (int k = 0; k < 4; ++k) o[k] = prev[k] + pv[k];
                }
                *(f32x4*)&xmy[gidx] = o;
            }
            __syncthreads();
        }
        if (p == 0) ISSUE_B(54, bB0);      // after final sync: fbuf reads done
    }
#undef ISSUE_A
#undef ISSUE_B
#undef ISSUE_WP
#undef WAITBAR
#undef LGKMBAR
}

// ---------------- K6: MFMA GDN, 2x128 px tiles ----------------
__global__ __launch_bounds__(512, 2) void k_gdn(
    const short* __restrict__ gb, const float* __restrict__ beta,
    const float* __restrict__ mh, float* __restrict__ dout)
{
    __shared__ __align__(16) char smem[101376];
    short* aB = (short*)smem;               // [256][104] 53,248
    short* bG = (short*)(smem + 53248);     // [192][104] 39,936
    float* fbuf = (float*)smem;             // [192][132]
    const float* y = dout + NOUT;

    const int blk = blockIdx.x;             // 256 = 4b * 64 row-pairs
    const int b = blk >> 6;
    const int row0 = (blk & 63) * 2;
    const int t = threadIdx.x;
    const int w = t >> 6, l = t & 63;
    const int wm = w >> 1, we_ = w & 1;
    const int m0 = wm * 64;
    const int lo = l & 15, hi = l >> 4;

    f32x4 acc[4][6];
    #pragma unroll
    for (int a = 0; a < 4; ++a)
        #pragma unroll
        for (int n = 0; n < 6; ++n) acc[a][n] = (f32x4){0.f,0.f,0.f,0.f};

    #pragma unroll 1
    for (int ch = 0; ch < 2; ++ch) {
        __syncthreads();
        #pragma unroll 1
        for (int it = 0; it < 12; ++it) {
            int q = it*512 + t;                 // 6144 = 96c x 64 px-chunks
            int cL = q >> 6, px4 = (q & 63) << 2;
            int c = ch*96 + cL;
            int pi = px4 >> 7, pj = px4 & 127;
            f32x4 yv = *(const f32x4*)&y[((size_t)(b*C_ + c))*HW + (size_t)(row0+pi)*128 + pj];
            #pragma unroll
            for (int k = 0; k < 4; ++k)
                aB[(px4+k)*104 + cL] = (short)f2bf(yv[k]*yv[k]);
        }
        #pragma unroll 1
        for (int it = 0; it < 5; ++it) {
            int q = it*512 + t;
            if (q < 2304) {
                int co = q / 12, e8 = q - co*12;
                *(bf16x8*)&bG[co*104 + e8*8] = *(const bf16x8*)&gb[co*192 + ch*96 + e8*8];
            }
        }
        __syncthreads();
        #pragma unroll
        for (int ks = 0; ks < 3; ++ks) {
            const int koff = ks*32 + hi*8;
            bf16x8 a[4], bb[6];
            #pragma unroll
            for (int af = 0; af < 4; ++af)
                a[af] = *(const bf16x8*)&aB[(m0 + af*16 + lo)*104 + koff];
            #pragma unroll
            for (int nf = 0; nf < 6; ++nf)
                bb[nf] = *(const bf16x8*)&bG[(we_*96 + nf*16 + lo)*104 + koff];
            #pragma unroll
            for (int af = 0; af < 4; ++af)
                #pragma unroll
                for (int nf = 0; nf < 6; ++nf)
                    acc[af][nf] = __builtin_amdgcn_mfma_f32_16x16x32_bf16(
                        a[af], bb[nf], acc[af][nf], 0, 0, 0);
        }
    }

    #pragma unroll 1
    for (int ph = 0; ph < 2; ++ph) {
        __syncthreads();
        if ((wm >> 1) == ph) {
            #pragma unroll
            for (int af = 0; af < 4; ++af)
                #pragma unroll
                for (int nf = 0; nf < 6; ++nf) {
                    int co = we_*96 + nf*16 + lo;
                    int pxl = (wm&1)*64 + af*16 + hi*4;
                    *(f32x4*)&fbuf[co*132 + pxl] = acc[af][nf];
                }
        }
        __syncthreads();
        #pragma unroll 1
        for (int it = 0; it < 12; ++it) {
            int q = it*512 + t;
            int co = q >> 5, px4 = (q & 31) << 2;
            size_t gidx = ((size_t)(b*C_ + co))*HW + (size_t)(row0+ph)*128 + px4;
            int pixg = b*HW + (row0+ph)*128 + px4;
            f32x4 nv = *(f32x4*)&fbuf[co*132 + px4];
            f32x4 yv = *(const f32x4*)&y[gidx];
            f32x4 mh4 = *(const f32x4*)&mh[pixg];
            float bt = beta[co];
            f32x4 o;
            #pragma unroll
            for (int k = 0; k < 4; ++k)
                o[k] = (mh4[k] > 0.f) ? yv[k]*rsqrtf(bt + nv[k]) : 0.f;
            *(f32x4*)&dout[gidx] = o;
            *(f32x4*)&dout[(size_t)NOUT + gidx] = mh4;   // final mask (y read above)
        }
    }
}

extern "C" void kernel_launch(void* const* d_in, const int* in_sizes, int n_in,
                              void* d_out, int out_size, void* d_ws, size_t ws_size,
                              hipStream_t stream)
{
    const float* ll = (const float*)d_in[0];
    const float* b1 = (const float*)d_in[1];
    const float* b2 = (const float*)d_in[2];
    const float* b3 = (const float*)d_in[3];
    const int* llm = (const int*)d_in[4];
    const int* m1i = (const int*)d_in[5];
    const int* m2i = (const int*)d_in[6];
    const int* m3i = (const int*)d_in[7];
    const float* wc    = (const float*)d_in[8];
    const float* bcast = (const float*)d_in[9];
    const float* we    = (const float*)d_in[10];
    const float* be    = (const float*)d_in[11];
    const float* wp    = (const float*)d_in[12];
    const float* bp    = (const float*)d_in[13];
    const float* gamma = (const float*)d_in[14];
    const float* beta  = (const float*)d_in[15];

    char* ws = (char*)d_ws;
    float* S   = (float*)(ws + OFF_S);
    float* fac = (float*)(ws + OFF_FAC);
    float* mh  = (float*)(ws + OFF_MH);
    unsigned char* mu  = (unsigned char*)(ws + OFF_MU);
    unsigned char* m1b = (unsigned char*)(ws + OFF_M1);
    short* web3 = (short*)(ws + OFF_WEB3);
    short* wpb3 = (short*)(ws + OFF_WPB3);
    short* gb   = (short*)(ws + OFF_GB);

    float* outF = (float*)d_out;
    float* pre = outF;              // [0:NOUT] pre -> xmT halo -> final out
    float* xm  = outF + NOUT;       // [NOUT:2NOUT] xm -> y (in-place) -> final mask
    short* xmT = (short*)d_out;

    k_wcvt<<<dim3(5904), dim3(256), 0, stream>>>(we, wp, gamma, web3, wpb3, gb);
    k_idwt<<<dim3(B_*C_), dim3(512), 0, stream>>>(ll, b1, b2, b3, llm, m1i, m2i, m3i, pre, mu);
    k_cast<<<dim3(6144), dim3(256), 0, stream>>>(pre, mu, wc, bcast, xm, m1b);
    k_zhalo<<<dim3(194), dim3(256), 0, stream>>>(xmT);
    k_xmt<<<dim3(3072), dim3(256), 0, stream>>>(xm, xmT);
    k_rowsum<<<dim3(B_*H_), dim3(256), 0, stream>>>(m1b, S);
    k_facm<<<dim3(NPIX/256), dim3(256), 0, stream>>>(S, fac, mh);
    k_mbconv<<<dim3(512), dim3(512), 0, stream>>>(xmT, web3, wpb3, be, bp, bcast, fac, mh, m1b, xm);
    k_gdn<<<dim3(256), dim3(512), 0, stream>>>(gb, beta, mh, outF);
}

// Round 14
// 1949.718 us; speedup vs baseline: 1.8684x; 1.8684x over previous
//
#include <hip/hip_runtime.h>

#define B_   4
#define C_   192
#define E_   768
#define H0   64
#define H_   128
#define HW   (H_*H_)        // 16384
#define PLANE0 (H0*H0)      // 4096
#define NPIX (B_*HW)        // 65536
#define NOUT (B_*C_*HW)     // 12582912

// halo-padded pixel-major xm: [b][130][130][192] bf16, lives in d_out[0:NOUT]
#define XTW  130
#define XTPL (XTW*XTW)       // 16,900

// ws layout (bytes)
#define OFF_S    0u
#define OFF_FAC  262144u
#define OFF_MH   524288u
#define OFF_MU   786432u     // u8 3,145,728
#define OFF_M1   3932160u    // u8 12,582,912
#define OFF_WEB3 16515072u   // 108 tiles x [c8 4][e 384][8] bf16 = 2,654,208 (K-major)
#define OFF_WPB3 19169280u   // 12 chunks x [e8 8][co 192][8] bf16 = 294,912 (half/el-mapped)
#define OFF_GB   19464192u   // 192*192 bf16 = 73,728
// end 19,537,920

typedef __attribute__((ext_vector_type(8))) short bf16x8;
typedef __attribute__((ext_vector_type(4))) float f32x4;

__device__ __forceinline__ unsigned short f2bf(float f) {
    unsigned u = __float_as_uint(f);
    u += 0x7FFFu + ((u >> 16) & 1u);   // RNE
    return (unsigned short)(u >> 16);
}

__device__ __forceinline__ void gll16(const void* g, void* l) {
    __builtin_amdgcn_global_load_lds(
        (const __attribute__((address_space(1))) unsigned int*)g,
        (__attribute__((address_space(3))) unsigned int*)l, 16, 0, 0);
}

// ---------------- K0: zero halo ring of xmT ----------------
__global__ __launch_bounds__(256) void k_zhalo(short* __restrict__ xmT)
{
    int idx = blockIdx.x*256 + threadIdx.x;   // 4 * 516 * 24 = 49,536
    if (idx >= 49536) return;
    int g = idx % 24;
    int pp = (idx / 24) % 516;
    int b = idx / (24*516);
    int i, j;
    if (pp < 130)      { i = 0;   j = pp; }
    else if (pp < 260) { i = 129; j = pp - 130; }
    else { int q = pp - 260; i = 1 + (q >> 1); j = (q & 1) * 129; }
    *(bf16x8*)&xmT[((size_t)(b*XTPL + i*XTW + j))*192 + g*8] = (bf16x8)(short)0;
}

// ---------------- K1: partial IDWT + mask union (8 waves, parity-specialized) ----------------
__global__ __launch_bounds__(512) void k_idwt(
    const float* __restrict__ ll, const float* __restrict__ lh,
    const float* __restrict__ hl, const float* __restrict__ hh,
    const int* __restrict__ llm, const int* __restrict__ m1,
    const int* __restrict__ m2, const int* __restrict__ m3,
    float* __restrict__ pre, unsigned char* __restrict__ mu)
{
    const float G0c[7] = {-0.091271763114f,-0.057543526228f,0.591271763114f,1.115087052457f,
                          0.591271763114f,-0.057543526228f,-0.091271763114f};
    const float G1c[9] = {0.026748757411f,0.016864118443f,-0.078223266529f,-0.266864118443f,
                          0.602949018236f,-0.266864118443f,-0.078223266529f,0.016864118443f,
                          0.026748757411f};
    __shared__ float lo[H_*H0];
    __shared__ float hi[H_*H0];
    const int bc = blockIdx.x;
    const int base = bc * PLANE0;
    const int t = threadIdx.x;
    const int w = t >> 6, lane = t & 63;

    #pragma unroll 1
    for (int iter = 0; iter < 16; ++iter) {
        const int o = iter*8 + w;
        float alo = 0.f, ahi = 0.f;
        if (o & 1) {
            #pragma unroll
            for (int s = 0; s < 4; ++s) {
                int d = o - 3 + 2*s;
                if ((unsigned)d <= 126u) {
                    int q = base + (d >> 1)*H0 + lane;
                    float g0 = G0c[2*s], g1 = G1c[2*s + 1];
                    alo += g0 * ll[q]*(float)llm[q] + g1 * lh[q]*(float)m1[q];
                    ahi += g0 * hl[q]*(float)m2[q] + g1 * hh[q]*(float)m3[q];
                }
            }
        } else {
            #pragma unroll
            for (int s = 0; s < 5; ++s) {
                int d = o - 4 + 2*s;
                if ((unsigned)d <= 126u) {
                    int q = base + (d >> 1)*H0 + lane;
                    float g1 = G1c[2*s];
                    alo += g1 * lh[q]*(float)m1[q];
                    ahi += g1 * hh[q]*(float)m3[q];
                    if (s >= 1 && s <= 3) {
                        float g0 = G0c[2*s - 1];
                        alo += g0 * ll[q]*(float)llm[q];
                        ahi += g0 * hl[q]*(float)m2[q];
                    }
                }
            }
        }
        lo[o*H0 + lane] = alo;
        hi[o*H0 + lane] = ahi;
    }
    for (int idx = t; idx < PLANE0; idx += 512) {
        int q = base + idx;
        mu[q] = (unsigned char)((llm[q] | m1[q] | m2[q] | m3[q]) ? 1 : 0);
    }
    __syncthreads();

    const size_t ob = (size_t)bc * HW;
    const int c = lane;
    #pragma unroll 1
    for (int iter = 0; iter < 16; ++iter) {
        const int o = iter*8 + w;
        const float* lr = lo + o*H0;
        const float* hr = hi + o*H0;
        float lC  = lr[c];
        float hC  = hr[c];
        float lM1 = (c >= 1)  ? lr[c-1] : 0.f;
        float lP1 = (c <= 62) ? lr[c+1] : 0.f;
        float lP2 = (c <= 61) ? lr[c+2] : 0.f;
        float hM2 = (c >= 2)  ? hr[c-2] : 0.f;
        float hM1 = (c >= 1)  ? hr[c-1] : 0.f;
        float hP1 = (c <= 62) ? hr[c+1] : 0.f;
        float hP2 = (c <= 61) ? hr[c+2] : 0.f;
        float pe = G0c[1]*lM1 + G0c[3]*lC + G0c[5]*lP1
                 + G1c[0]*hM2 + G1c[2]*hM1 + G1c[4]*hC + G1c[6]*hP1 + G1c[8]*hP2;
        float po = G0c[0]*lM1 + G0c[2]*lC + G0c[4]*lP1 + G0c[6]*lP2
                 + G1c[1]*hM1 + G1c[3]*hC + G1c[5]*hP1 + G1c[7]*hP2;
        float2 pv = {pe, po};
        *(float2*)&pre[ob + (size_t)o*H_ + 2*c] = pv;
    }
}

// ---------------- K2: depthwise 3x3 partial conv (cast), LDS-tiled ----------------
__global__ __launch_bounds__(256) void k_cast(
    const float* __restrict__ pre, const unsigned char* __restrict__ mu,
    const float* __restrict__ wc, const float* __restrict__ bcast,
    float* __restrict__ xm, unsigned char* __restrict__ m1out)
{
    __shared__ float sp[18*131];
    __shared__ float smv[10*66];
    const int blk = blockIdx.x;          // 6144 = 768 bc x 8 row-tiles
    const int bc = blk >> 3;
    const int i0 = (blk & 7) * 16;
    const int c = bc % C_;
    const int t = threadIdx.x;
    const size_t pb = (size_t)bc * HW;
    const size_t mb = (size_t)bc * PLANE0;
    for (int q = t; q < 2340; q += 256) {
        int rr = q / 130, cc = q - rr*130;
        int gi = i0 + rr - 1, gj = cc - 1;
        float v = 0.f;
        if ((unsigned)gi < 128u && (unsigned)gj < 128u) v = pre[pb + gi*128 + gj];
        sp[rr*131 + cc] = v;
    }
    for (int q = t; q < 660; q += 256) {
        int rr = q / 66, cc = q - rr*66;
        int mi = (i0 >> 1) + rr - 1, mj = cc - 1;
        float v = 0.f;
        if ((unsigned)mi < 64u && (unsigned)mj < 64u) v = (float)mu[mb + mi*64 + mj];
        smv[rr*66 + cc] = v;
    }
    __syncthreads();
    float w9[9];
    #pragma unroll
    for (int k = 0; k < 9; ++k) w9[k] = wc[c*9 + k];
    const float bcc = bcast[c];
    const int rr = t >> 4, c8 = (t & 15) * 8;
    float ox[8]; unsigned mo = 0, mo2 = 0;
    #pragma unroll
    for (int u = 0; u < 8; ++u) {
        int j = c8 + u;
        float o = 0.f, s = 0.f;
        #pragma unroll
        for (int di = 0; di < 3; ++di) {
            int gi = i0 + rr + di - 1;
            int mrow = (gi >> 1) - (i0 >> 1) + 1;
            #pragma unroll
            for (int dj = 0; dj < 3; ++dj) {
                int gj = j + dj - 1;
                float m0v = smv[mrow*66 + (gj >> 1) + 1];
                s += m0v;
                o += m0v * sp[(rr+di)*131 + j + dj] * w9[di*3 + dj];
            }
        }
        bool valid = s > 0.f;
        ox[u] = valid ? (o * (9.f / s) + bcc) : 0.f;
        unsigned bit = valid ? 1u : 0u;
        if (u < 4) mo |= bit << (8*u); else mo2 |= bit << (8*(u-4));
    }
    size_t oidx = pb + (size_t)(i0 + rr)*128 + c8;
    f32x4 v0 = {ox[0], ox[1], ox[2], ox[3]};
    f32x4 v1 = {ox[4], ox[5], ox[6], ox[7]};
    *(f32x4*)&xm[oidx] = v0;
    *(f32x4*)&xm[oidx + 4] = v1;
    *(unsigned*)&m1out[oidx] = mo;
    *(unsigned*)&m1out[oidx + 4] = mo2;
}

// ---------------- K3: channel-sum of mask1 ----------------
__global__ __launch_bounds__(256) void k_rowsum(const unsigned char* __restrict__ m1,
                                                float* __restrict__ S)
{
    __shared__ float red[128];
    int bi = blockIdx.x;                // b*128 + i
    int b = bi >> 7, i = bi & 127;
    int t = threadIdx.x;
    int j = t & 127, half = t >> 7;
    float s = 0.f;
    size_t base = (size_t)b*C_*HW + (size_t)(half*96)*HW + (size_t)i*H_ + j;
    for (int c = 0; c < 96; ++c) s += (float)m1[base + (size_t)c*HW];
    if (half) red[j] = s;
    __syncthreads();
    if (!half) S[bi*H_ + j] = s + red[j];
}

// ---------------- K4: window-sum -> expand factor & mh ----------------
__global__ __launch_bounds__(256) void k_facm(const float* __restrict__ S,
                                              float* __restrict__ fac, float* __restrict__ mh)
{
    int px = blockIdx.x*256 + threadIdx.x;
    if (px >= NPIX) return;
    int j = px & 127, i = (px >> 7) & 127, b = px >> 14;
    float w3 = 0.f;
    #pragma unroll
    for (int di = -1; di <= 1; ++di) {
        int gi = i + di; if ((unsigned)gi >= (unsigned)H_) continue;
        #pragma unroll
        for (int dj = -1; dj <= 1; ++dj) {
            int gj = j + dj; if ((unsigned)gj >= (unsigned)H_) continue;
            w3 += S[(b*H_ + gi)*H_ + gj];
        }
    }
    bool v = w3 > 0.f;
    fac[px] = v ? 1728.f / w3 : 0.f;
    mh[px]  = v ? 1.f : 0.f;
}

// ---------------- K4b: weight convert + permute (K-major) ----------------
// web3: tile = p*54 + sc*9 + r, layout [c8 4][e 384][j 8]:
//   value = we[(p*384+e)*1728 + (sc*32 + c8*8 + j)*9 + r]
// wpb3: chunk = p*6 + h*3 + c3, layout [e8 8][co 192][8]; el = c3*64 + e8*8 + j;
//   e = p*384 + (el/48)*96 + h*48 + (el%48);  value = wp[co*768 + e]
// gb  : gamma bf16 [co][c]
__global__ __launch_bounds__(256) void k_wcvt(const float* __restrict__ we,
                                              const float* __restrict__ wp,
                                              const float* __restrict__ gamma,
                                              short* __restrict__ web3,
                                              short* __restrict__ wpb3,
                                              short* __restrict__ gb)
{
    int idx = blockIdx.x*256 + threadIdx.x;
    const int N1 = 108*12288;        // 1,327,104
    const int N2 = 12*12288;         // 147,456
    if (idx < N1) {
        int tile = idx / 12288, rem = idx % 12288;
        int g = rem >> 3, j = rem & 7;
        int c8 = g / 384, e = g % 384;
        int p = tile / 54, sc = (tile % 54) / 9, r = tile % 9;
        web3[idx] = (short)f2bf(we[(size_t)(p*384 + e)*1728 + (sc*32 + c8*8 + j)*9 + r]);
    } else if (idx < N1 + N2) {
        int i2 = idx - N1;
        int chunk = i2 / 12288, rem = i2 % 12288;
        int g = rem >> 3, j = rem & 7;
        int e8 = g / 192, co = g % 192;
        int p = chunk / 6, hf = (chunk % 6) / 3, c3 = chunk % 3;
        int el = c3*64 + e8*8 + j;
        int e = p*384 + (el/48)*96 + hf*48 + (el%48);
        wpb3[i2] = (short)f2bf(wp[(size_t)co*E_ + e]);
    } else {
        int i3 = idx - N1 - N2;
        if (i3 < C_*C_) gb[i3] = (short)f2bf(gamma[i3]);
    }
}

// ---------------- K4c: xm f32 [c][pix] -> xmT bf16 [b][130][130][192] (interior) ----------------
__global__ __launch_bounds__(256) void k_xmt(const float* __restrict__ xm,
                                             short* __restrict__ xmT)
{
    __shared__ float sm[64*65];
    const int gx = blockIdx.x;           // 3072 = 3 cb * 1024 pb
    const int cb = gx >> 10, pb = gx & 1023;
    const int c0 = cb*64, pix0 = pb*64;
    const int b = pix0 >> 14, pixb = pix0 & 16383;
    const int t = threadIdx.x;
    const int lane6 = t & 63, hi4 = t >> 6;
    #pragma unroll
    for (int it = 0; it < 16; ++it) {
        int r4 = it*4 + hi4;
        sm[r4*65 + lane6] = xm[((size_t)(b*C_ + c0 + r4))*HW + pixb + lane6];
    }
    __syncthreads();
    #pragma unroll
    for (int it = 0; it < 2; ++it) {
        int q = it*256 + t;
        int pp = q >> 3, c8 = q & 7;
        int p = pixb + pp;
        int i = p >> 7, j = p & 127;
        bf16x8 v;
        #pragma unroll
        for (int jj = 0; jj < 8; ++jj) v[jj] = (short)f2bf(sm[(c8*8+jj)*65 + pp]);
        *(bf16x8*)&xmT[((size_t)(b*XTPL + (i+1)*XTW + (j+1)))*192 + c0 + c8*8] = v;
    }
}

// ---------------- K5: MFMA fused MBConv — 74KB LDS, 2 blocks/CU ----------------
// 512 blocks x 512 thr. 2 e-passes of 384; 54 taps/pass; 2-buffer B (issue-after-drain);
// single junk-padded apat (uniform 2-gll); silu/proj in 2 halves of 192e; hB row-pad 1032.
// NOTE: __launch_bounds__ 2nd arg acts as min BLOCKS/CU on hipcc (r13 evidence: 4 -> 64-VGPR cap).
__global__ __launch_bounds__(512, 2) void k_mbconv(
    const short* __restrict__ xmT, const short* __restrict__ web3,
    const short* __restrict__ wpb3, const float* __restrict__ be,
    const float* __restrict__ bp, const float* __restrict__ bcast,
    const float* __restrict__ fac, const float* __restrict__ mh,
    const unsigned char* __restrict__ m1, float* __restrict__ xmy)
{
    __shared__ __align__(16) char smem[74112];
    // expand: apat @0 [c8 4][256 pos][8] 16,384 (pos>=180 junk) | bB @16,384 [2][12288sh] 49,152 -> 65,536
    // proj:   hB @0 [el8 24][stride 1032 sh] 49,536 | wpB @49,536 [12288sh] 24,576 -> 74,112
    // epi:    fbuf @0 [192][68] f32 52,224
    short* apat = (short*)smem;
    short* bB0  = (short*)(smem + 16384);
    short* bB1  = (short*)(smem + 16384 + 24576);
    short* hB   = (short*)smem;
    short* wpB  = (short*)(smem + 49536);
    float* fbuf = (float*)smem;

    // XCD-aware swizzle: 512 blocks = 8 XCDs x 64 contiguous
    const int blk = (blockIdx.x & 7)*64 + (blockIdx.x >> 3);
    const int b = blk >> 7;                       // 4b x 16ti x 8tj
    const int ti = (blk >> 3) & 15, tj = blk & 7;
    const int i0 = ti*8, j0 = tj*16;              // tile = 8 rows x 16 cols
    const int t = threadIdx.x;
    const int w = t >> 6, l = t & 63;
    const int wm2 = w >> 2, we2 = w & 3;
    const int m0 = wm2 * 64;
    const int lo = l & 15, hi = l >> 4;

// uniform A staging: 1024 granules = 2 gll/thread; [c8 4][256]; pos>=180 reads junk (in-bounds)
#define ISSUE_A(sc_) do {                                                       \
    const int c0_ = (sc_)*32;                                                   \
    _Pragma("unroll")                                                           \
    for (int it_ = 0; it_ < 2; ++it_) {                                         \
        int q_ = it_*512 + t;                                                   \
        int c8_ = q_ >> 8, pos_ = q_ & 255;                                     \
        int rr_ = pos_/18, cc_ = pos_ - rr_*18;                                 \
        gll16(&xmT[((size_t)(b*XTPL + (i0+rr_)*XTW + (j0+cc_)))*192 + c0_       \
                   + c8_*8], &apat[q_*8]);                                      \
    }                                                                           \
} while(0)

#define ISSUE_B(tileIdx_, dst_) do {                                            \
    const size_t off_ = (size_t)(tileIdx_) * 12288;                             \
    _Pragma("unroll")                                                           \
    for (int it_ = 0; it_ < 3; ++it_) {                                         \
        int q_ = it_*512 + t;                                                   \
        gll16(&web3[off_ + q_*8], &(dst_)[q_*8]);                               \
    }                                                                           \
} while(0)

#define ISSUE_WP(chunkIdx_) do {                                                \
    const size_t off_ = (size_t)(chunkIdx_) * 12288;                            \
    _Pragma("unroll")                                                           \
    for (int it_ = 0; it_ < 3; ++it_) {                                         \
        int q_ = it_*512 + t;                                                   \
        gll16(&wpb3[off_ + q_*8], &wpB[q_*8]);                                  \
    }                                                                           \
} while(0)

#define WAITBAR(N_) do {                                                        \
    asm volatile("s_waitcnt vmcnt(" #N_ ") lgkmcnt(0)" ::: "memory");           \
    __builtin_amdgcn_s_barrier();                                               \
    __builtin_amdgcn_sched_barrier(0);                                          \
} while(0)

#define LGKMBAR() do {                                                          \
    asm volatile("s_waitcnt lgkmcnt(0)" ::: "memory");                          \
    __builtin_amdgcn_s_barrier();                                               \
    __builtin_amdgcn_sched_barrier(0);                                          \
} while(0)

    float facr[4][4];
    #pragma unroll
    for (int af = 0; af < 4; ++af)
        #pragma unroll
        for (int reg = 0; reg < 4; ++reg) {
            int px = m0 + af*16 + hi*4 + reg;
            facr[af][reg] = fac[b*HW + (i0 + (px >> 4))*128 + j0 + (px & 15)];
        }
    // per-thread invariant LDS bases (short indices)
    int aoffS[4], boffS[6], hpxS[4], wcoS[3];
    #pragma unroll
    for (int af = 0; af < 4; ++af) {
        int px = m0 + af*16 + lo;
        aoffS[af] = (hi*256 + (px >> 4)*18 + (px & 15)) * 8;
        hpxS[af]  = px * 8;
    }
    #pragma unroll
    for (int nf = 0; nf < 6; ++nf)
        boffS[nf] = (hi*384 + we2*96 + nf*16 + lo) * 8;
    #pragma unroll
    for (int nf = 0; nf < 3; ++nf)
        wcoS[nf] = (we2*48 + nf*16 + lo) * 8;
    const int hrowS = hi * 1032;     // + (c3*8+ks*4)*1032 immediate
    const int wrowS = hi * 1536;     // + ks*4*1536 immediate (1536 shorts = 192co*8)

    // prologue
    ISSUE_B(0, bB0);

    #pragma unroll 1
    for (int p = 0; p < 2; ++p) {
        // ================= expand: 54 taps =================
        f32x4 acc[4][6];
        #pragma unroll
        for (int a = 0; a < 4; ++a)
            #pragma unroll
            for (int n = 0; n < 6; ++n) acc[a][n] = (f32x4){0.f,0.f,0.f,0.f};

        #pragma unroll 1
        for (int sc = 0; sc < 6; ++sc) {
            const int tbase = p*54 + sc*9;
            const int scp = sc & 1;
            #pragma unroll
            for (int r = 0; r < 9; ++r) {
                const int rv = (r/3)*18 + (r%3);            // compile-time
                short* bcur = ((scp ^ (r & 1)) ? bB1 : bB0);
                short* bnxt = ((scp ^ (r & 1)) ? bB0 : bB1);
                if (r == 0) {
                    WAITBAR(0);                 // B(tile) landed; apat reads done
                    ISSUE_A(sc);
                    ISSUE_B(tbase + 1, bnxt);
                    asm volatile("s_waitcnt vmcnt(3) lgkmcnt(0)" ::: "memory");
                    __builtin_amdgcn_s_barrier();
                    __builtin_amdgcn_sched_barrier(0);
                } else {
                    WAITBAR(0);                 // B(tile) landed; bnxt reads (r-2) done
                    if (!(sc == 5 && r == 8)) ISSUE_B(tbase + r + 1, bnxt);
                }
                bf16x8 a[4], bb[6];
                #pragma unroll
                for (int af = 0; af < 4; ++af)
                    a[af] = *(const bf16x8*)&apat[aoffS[af] + rv*8];
                #pragma unroll
                for (int nf = 0; nf < 6; ++nf)
                    bb[nf] = *(const bf16x8*)&bcur[boffS[nf]];
                __builtin_amdgcn_s_setprio(1);
                #pragma unroll
                for (int af = 0; af < 4; ++af)
                    #pragma unroll
                    for (int nf = 0; nf < 6; ++nf)
                        acc[af][nf] = __builtin_amdgcn_mfma_f32_16x16x32_bf16(
                            a[af], bb[nf], acc[af][nf], 0, 0, 0);
                __builtin_amdgcn_s_setprio(0);
            }
        }

        // ================= proj: 2 halves x (silu + 3 chunks of 64e) =================
        f32x4 accy[4][3];
        #pragma unroll
        for (int a = 0; a < 4; ++a)
            #pragma unroll
            for (int n = 0; n < 3; ++n) accy[a][n] = (f32x4){0.f,0.f,0.f,0.f};

        #pragma unroll 1
        for (int h = 0; h < 2; ++h) {
            LGKMBAR();      // h0: tap53 reads done (apat/bB dead); h1: h0 proj reads done
            // silu half h -> hB (rows el8 0..23, stride 1032)
            #pragma unroll
            for (int n3 = 0; n3 < 3; ++n3) {
                const int nf = h*3 + n3;
                int el = we2*48 + n3*16 + lo;
                int e_glob = we2*96 + h*48 + n3*16 + lo;
                float bev = be[p*384 + e_glob];
                int hb = (el >> 3)*1032 + (el & 7);
                #pragma unroll
                for (int af = 0; af < 4; ++af)
                    #pragma unroll
                    for (int reg = 0; reg < 4; ++reg) {
                        int px = m0 + af*16 + hi*4 + reg;
                        float fr = facr[af][reg];
                        float v = acc[af][nf][reg]*fr + bev;
                        float hv = (fr > 0.f) ? v / (1.f + __expf(-v)) : 0.f;
                        hB[hb + px*8] = (short)f2bf(hv);
                    }
            }
            #pragma unroll 1
            for (int c3 = 0; c3 < 3; ++c3) {
                if (c3 > 0) LGKMBAR();          // prev chunk reads done before wpB overwrite
                ISSUE_WP(p*6 + h*3 + c3);
                asm volatile("s_waitcnt vmcnt(0) lgkmcnt(0)" ::: "memory");
                __builtin_amdgcn_s_barrier();
                __builtin_amdgcn_sched_barrier(0);
                #pragma unroll
                for (int ks = 0; ks < 2; ++ks) {
                    bf16x8 a[4], bb[3];
                    #pragma unroll
                    for (int af = 0; af < 4; ++af)
                        a[af] = *(const bf16x8*)&hB[(c3*8 + ks*4)*1032 + hrowS + hpxS[af]];
                    #pragma unroll
                    for (int nf = 0; nf < 3; ++nf)
                        bb[nf] = *(const bf16x8*)&wpB[ks*4*1536 + wrowS + wcoS[nf]];
                    __builtin_amdgcn_s_setprio(1);
                    #pragma unroll
                    for (int af = 0; af < 4; ++af)
                        #pragma unroll
                        for (int nf = 0; nf < 3; ++nf)
                            accy[af][nf] = __builtin_amdgcn_mfma_f32_16x16x32_bf16(
                                a[af], bb[nf], accy[af][nf], 0, 0, 0);
                    __builtin_amdgcn_s_setprio(0);
                }
            }
        }

        // ================= per-pass y accumulate =================
        LGKMBAR();                         // last proj reads done; hB/wpB dead
        #pragma unroll 1
        for (int ph = 0; ph < 2; ++ph) {
            if (wm2 == ph) {
                #pragma unroll
                for (int af = 0; af < 4; ++af)
                    #pragma unroll
                    for (int nf = 0; nf < 3; ++nf) {
                        int co = we2*48 + nf*16 + lo;
                        int pxl = af*16 + hi*4;
                        *(f32x4*)&fbuf[co*68 + pxl] = accy[af][nf];
                    }
            }
            __syncthreads();
            #pragma unroll 1
            for (int it = 0; it < 6; ++it) {
                int q = it*512 + t;              // 3072 = 192co x 16 px-quads
                int co = q >> 4, px4 = (q & 15) << 2;
                int px = ph*64 + px4;
                int pi = px >> 4, pj = px & 15;
                size_t gidx = ((size_t)(b*C_ + co))*HW + (size_t)(i0+pi)*128 + j0 + pj;
                f32x4 pv = *(f32x4*)&fbuf[co*68 + px4];
                f32x4 prev = *(const f32x4*)&xmy[gidx];
                f32x4 o;
                if (p == 0) {
                    int pixg = b*HW + (i0+pi)*128 + j0 + pj;
                    f32x4 mh4 = *(const f32x4*)&mh[pixg];
                    unsigned mu4 = *(const unsigned*)&m1[gidx];
                    float bpc = bp[co], bcc = bcast[co];
                    #pragma unroll
                    for (int k = 0; k < 4; ++k)
                        o[k] = pv[k] + bpc + prev[k] + bcc*(mh4[k] - (float)((mu4 >> (8*k)) & 255u));
                } else {
                    #pragma unroll
                    for (int k = 0; k < 4; ++k) o[k] = prev[k] + pv[k];
                }
                *(f32x4*)&xmy[gidx] = o;
            }
            __syncthreads();
        }
        if (p == 0) ISSUE_B(54, bB0);      // after final sync: fbuf reads done
    }
#undef ISSUE_A
#undef ISSUE_B
#undef ISSUE_WP
#undef WAITBAR
#undef LGKMBAR
}

// ---------------- K6: MFMA GDN, 2x128 px tiles ----------------
__global__ __launch_bounds__(512, 2) void k_gdn(
    const short* __restrict__ gb, const float* __restrict__ beta,
    const float* __restrict__ mh, float* __restrict__ dout)
{
    __shared__ __align__(16) char smem[101376];
    short* aB = (short*)smem;               // [256][104] 53,248
    short* bG = (short*)(smem + 53248);     // [192][104] 39,936
    float* fbuf = (float*)smem;             // [192][132]
    const float* y = dout + NOUT;

    const int blk = blockIdx.x;             // 256 = 4b * 64 row-pairs
    const int b = blk >> 6;
    const int row0 = (blk & 63) * 2;
    const int t = threadIdx.x;
    const int w = t >> 6, l = t & 63;
    const int wm = w >> 1, we_ = w & 1;
    const int m0 = wm * 64;
    const int lo = l & 15, hi = l >> 4;

    f32x4 acc[4][6];
    #pragma unroll
    for (int a = 0; a < 4; ++a)
        #pragma unroll
        for (int n = 0; n < 6; ++n) acc[a][n] = (f32x4){0.f,0.f,0.f,0.f};

    #pragma unroll 1
    for (int ch = 0; ch < 2; ++ch) {
        __syncthreads();
        #pragma unroll 1
        for (int it = 0; it < 12; ++it) {
            int q = it*512 + t;                 // 6144 = 96c x 64 px-chunks
            int cL = q >> 6, px4 = (q & 63) << 2;
            int c = ch*96 + cL;
            int pi = px4 >> 7, pj = px4 & 127;
            f32x4 yv = *(const f32x4*)&y[((size_t)(b*C_ + c))*HW + (size_t)(row0+pi)*128 + pj];
            #pragma unroll
            for (int k = 0; k < 4; ++k)
                aB[(px4+k)*104 + cL] = (short)f2bf(yv[k]*yv[k]);
        }
        #pragma unroll 1
        for (int it = 0; it < 5; ++it) {
            int q = it*512 + t;
            if (q < 2304) {
                int co = q / 12, e8 = q - co*12;
                *(bf16x8*)&bG[co*104 + e8*8] = *(const bf16x8*)&gb[co*192 + ch*96 + e8*8];
            }
        }
        __syncthreads();
        #pragma unroll
        for (int ks = 0; ks < 3; ++ks) {
            const int koff = ks*32 + hi*8;
            bf16x8 a[4], bb[6];
            #pragma unroll
            for (int af = 0; af < 4; ++af)
                a[af] = *(const bf16x8*)&aB[(m0 + af*16 + lo)*104 + koff];
            #pragma unroll
            for (int nf = 0; nf < 6; ++nf)
                bb[nf] = *(const bf16x8*)&bG[(we_*96 + nf*16 + lo)*104 + koff];
            #pragma unroll
            for (int af = 0; af < 4; ++af)
                #pragma unroll
                for (int nf = 0; nf < 6; ++nf)
                    acc[af][nf] = __builtin_amdgcn_mfma_f32_16x16x32_bf16(
                        a[af], bb[nf], acc[af][nf], 0, 0, 0);
        }
    }

    #pragma unroll 1
    for (int ph = 0; ph < 2; ++ph) {
        __syncthreads();
        if ((wm >> 1) == ph) {
            #pragma unroll
            for (int af = 0; af < 4; ++af)
                #pragma unroll
                for (int nf = 0; nf < 6; ++nf) {
                    int co = we_*96 + nf*16 + lo;
                    int pxl = (wm&1)*64 + af*16 + hi*4;
                    *(f32x4*)&fbuf[co*132 + pxl] = acc[af][nf];
                }
        }
        __syncthreads();
        #pragma unroll 1
        for (int it = 0; it < 12; ++it) {
            int q = it*512 + t;
            int co = q >> 5, px4 = (q & 31) << 2;
            size_t gidx = ((size_t)(b*C_ + co))*HW + (size_t)(row0+ph)*128 + px4;
            int pixg = b*HW + (row0+ph)*128 + px4;
            f32x4 nv = *(f32x4*)&fbuf[co*132 + px4];
            f32x4 yv = *(const f32x4*)&y[gidx];
            f32x4 mh4 = *(const f32x4*)&mh[pixg];
            float bt = beta[co];
            f32x4 o;
            #pragma unroll
            for (int k = 0; k < 4; ++k)
                o[k] = (mh4[k] > 0.f) ? yv[k]*rsqrtf(bt + nv[k]) : 0.f;
            *(f32x4*)&dout[gidx] = o;
            *(f32x4*)&dout[(size_t)NOUT + gidx] = mh4;   // final mask (y read above)
        }
    }
}

extern "C" void kernel_launch(void* const* d_in, const int* in_sizes, int n_in,
                              void* d_out, int out_size, void* d_ws, size_t ws_size,
                              hipStream_t stream)
{
    const float* ll = (const float*)d_in[0];
    const float* b1 = (const float*)d_in[1];
    const float* b2 = (const float*)d_in[2];
    const float* b3 = (const float*)d_in[3];
    const int* llm = (const int*)d_in[4];
    const int* m1i = (const int*)d_in[5];
    const int* m2i = (const int*)d_in[6];
    const int* m3i = (const int*)d_in[7];
    const float* wc    = (const float*)d_in[8];
    const float* bcast = (const float*)d_in[9];
    const float* we    = (const float*)d_in[10];
    const float* be    = (const float*)d_in[11];
    const float* wp    = (const float*)d_in[12];
    const float* bp    = (const float*)d_in[13];
    const float* gamma = (const float*)d_in[14];
    const float* beta  = (const float*)d_in[15];

    char* ws = (char*)d_ws;
    float* S   = (float*)(ws + OFF_S);
    float* fac = (float*)(ws + OFF_FAC);
    float* mh  = (float*)(ws + OFF_MH);
    unsigned char* mu  = (unsigned char*)(ws + OFF_MU);
    unsigned char* m1b = (unsigned char*)(ws + OFF_M1);
    short* web3 = (short*)(ws + OFF_WEB3);
    short* wpb3 = (short*)(ws + OFF_WPB3);
    short* gb   = (short*)(ws + OFF_GB);

    float* outF = (float*)d_out;
    float* pre = outF;              // [0:NOUT] pre -> xmT halo -> final out
    float* xm  = outF + NOUT;       // [NOUT:2NOUT] xm -> y (in-place) -> final mask
    short* xmT = (short*)d_out;

    k_wcvt<<<dim3(5904), dim3(256), 0, stream>>>(we, wp, gamma, web3, wpb3, gb);
    k_idwt<<<dim3(B_*C_), dim3(512), 0, stream>>>(ll, b1, b2, b3, llm, m1i, m2i, m3i, pre, mu);
    k_cast<<<dim3(6144), dim3(256), 0, stream>>>(pre, mu, wc, bcast, xm, m1b);
    k_zhalo<<<dim3(194), dim3(256), 0, stream>>>(xmT);
    k_xmt<<<dim3(3072), dim3(256), 0, stream>>>(xm, xmT);
    k_rowsum<<<dim3(B_*H_), dim3(256), 0, stream>>>(m1b, S);
    k_facm<<<dim3(NPIX/256), dim3(256), 0, stream>>>(S, fac, mh);
    k_mbconv<<<dim3(512), dim3(512), 0, stream>>>(xmT, web3, wpb3, be, bp, bcast, fac, mh, m1b, xm);
    k_gdn<<<dim3(256), dim3(512), 0, stream>>>(gb, beta, mh, outF);
}

// Round 15
// 490.893 us; speedup vs baseline: 7.4208x; 3.9718x over previous
//
#include <hip/hip_runtime.h>

#define B_   4
#define C_   192
#define E_   768
#define H0   64
#define H_   128
#define HW   (H_*H_)        // 16384
#define PLANE0 (H0*H0)      // 4096
#define NPIX (B_*HW)        // 65536
#define NOUT (B_*C_*HW)     // 12582912

// halo-padded pixel-major xm: [b][130][130][192] bf16, lives in d_out[0:NOUT]
#define XTW  130
#define XTPL (XTW*XTW)       // 16,900

// ws layout (bytes)
#define OFF_S    0u
#define OFF_FAC  262144u
#define OFF_MH   524288u
#define OFF_MU   786432u     // u8 3,145,728
#define OFF_M1   3932160u    // u8 12,582,912
#define OFF_WEB3 16515072u   // 108 tiles x [c8 4][e 384][8] bf16 = 2,654,208 (K-major)
#define OFF_WPB3 19169280u   // 12 chunks x [e8 8][co 192][8] bf16 = 294,912 (half/el-mapped)
#define OFF_GB   19464192u   // 192*192 bf16 = 73,728
// end 19,537,920

typedef __attribute__((ext_vector_type(8))) short bf16x8;
typedef __attribute__((ext_vector_type(4))) float f32x4;

__device__ __forceinline__ unsigned short f2bf(float f) {
    unsigned u = __float_as_uint(f);
    u += 0x7FFFu + ((u >> 16) & 1u);   // RNE
    return (unsigned short)(u >> 16);
}

__device__ __forceinline__ void gll16(const void* g, void* l) {
    __builtin_amdgcn_global_load_lds(
        (const __attribute__((address_space(1))) unsigned int*)g,
        (__attribute__((address_space(3))) unsigned int*)l, 16, 0, 0);
}

// ---------------- K0: zero halo ring of xmT ----------------
__global__ __launch_bounds__(256) void k_zhalo(short* __restrict__ xmT)
{
    int idx = blockIdx.x*256 + threadIdx.x;   // 4 * 516 * 24 = 49,536
    if (idx >= 49536) return;
    int g = idx % 24;
    int pp = (idx / 24) % 516;
    int b = idx / (24*516);
    int i, j;
    if (pp < 130)      { i = 0;   j = pp; }
    else if (pp < 260) { i = 129; j = pp - 130; }
    else { int q = pp - 260; i = 1 + (q >> 1); j = (q & 1) * 129; }
    *(bf16x8*)&xmT[((size_t)(b*XTPL + i*XTW + j))*192 + g*8] = (bf16x8)(short)0;
}

// ---------------- K1: partial IDWT + mask union (8 waves, parity-specialized) ----------------
__global__ __launch_bounds__(512) void k_idwt(
    const float* __restrict__ ll, const float* __restrict__ lh,
    const float* __restrict__ hl, const float* __restrict__ hh,
    const int* __restrict__ llm, const int* __restrict__ m1,
    const int* __restrict__ m2, const int* __restrict__ m3,
    float* __restrict__ pre, unsigned char* __restrict__ mu)
{
    const float G0c[7] = {-0.091271763114f,-0.057543526228f,0.591271763114f,1.115087052457f,
                          0.591271763114f,-0.057543526228f,-0.091271763114f};
    const float G1c[9] = {0.026748757411f,0.016864118443f,-0.078223266529f,-0.266864118443f,
                          0.602949018236f,-0.266864118443f,-0.078223266529f,0.016864118443f,
                          0.026748757411f};
    __shared__ float lo[H_*H0];
    __shared__ float hi[H_*H0];
    const int bc = blockIdx.x;
    const int base = bc * PLANE0;
    const int t = threadIdx.x;
    const int w = t >> 6, lane = t & 63;

    #pragma unroll 1
    for (int iter = 0; iter < 16; ++iter) {
        const int o = iter*8 + w;
        float alo = 0.f, ahi = 0.f;
        if (o & 1) {
            #pragma unroll
            for (int s = 0; s < 4; ++s) {
                int d = o - 3 + 2*s;
                if ((unsigned)d <= 126u) {
                    int q = base + (d >> 1)*H0 + lane;
                    float g0 = G0c[2*s], g1 = G1c[2*s + 1];
                    alo += g0 * ll[q]*(float)llm[q] + g1 * lh[q]*(float)m1[q];
                    ahi += g0 * hl[q]*(float)m2[q] + g1 * hh[q]*(float)m3[q];
                }
            }
        } else {
            #pragma unroll
            for (int s = 0; s < 5; ++s) {
                int d = o - 4 + 2*s;
                if ((unsigned)d <= 126u) {
                    int q = base + (d >> 1)*H0 + lane;
                    float g1 = G1c[2*s];
                    alo += g1 * lh[q]*(float)m1[q];
                    ahi += g1 * hh[q]*(float)m3[q];
                    if (s >= 1 && s <= 3) {
                        float g0 = G0c[2*s - 1];
                        alo += g0 * ll[q]*(float)llm[q];
                        ahi += g0 * hl[q]*(float)m2[q];
                    }
                }
            }
        }
        lo[o*H0 + lane] = alo;
        hi[o*H0 + lane] = ahi;
    }
    for (int idx = t; idx < PLANE0; idx += 512) {
        int q = base + idx;
        mu[q] = (unsigned char)((llm[q] | m1[q] | m2[q] | m3[q]) ? 1 : 0);
    }
    __syncthreads();

    const size_t ob = (size_t)bc * HW;
    const int c = lane;
    #pragma unroll 1
    for (int iter = 0; iter < 16; ++iter) {
        const int o = iter*8 + w;
        const float* lr = lo + o*H0;
        const float* hr = hi + o*H0;
        float lC  = lr[c];
        float hC  = hr[c];
        float lM1 = (c >= 1)  ? lr[c-1] : 0.f;
        float lP1 = (c <= 62) ? lr[c+1] : 0.f;
        float lP2 = (c <= 61) ? lr[c+2] : 0.f;
        float hM2 = (c >= 2)  ? hr[c-2] : 0.f;
        float hM1 = (c >= 1)  ? hr[c-1] : 0.f;
        float hP1 = (c <= 62) ? hr[c+1] : 0.f;
        float hP2 = (c <= 61) ? hr[c+2] : 0.f;
        float pe = G0c[1]*lM1 + G0c[3]*lC + G0c[5]*lP1
                 + G1c[0]*hM2 + G1c[2]*hM1 + G1c[4]*hC + G1c[6]*hP1 + G1c[8]*hP2;
        float po = G0c[0]*lM1 + G0c[2]*lC + G0c[4]*lP1 + G0c[6]*lP2
                 + G1c[1]*hM1 + G1c[3]*hC + G1c[5]*hP1 + G1c[7]*hP2;
        float2 pv = {pe, po};
        *(float2*)&pre[ob + (size_t)o*H_ + 2*c] = pv;
    }
}

// ---------------- K2: depthwise 3x3 partial conv (cast), LDS-tiled ----------------
__global__ __launch_bounds__(256) void k_cast(
    const float* __restrict__ pre, const unsigned char* __restrict__ mu,
    const float* __restrict__ wc, const float* __restrict__ bcast,
    float* __restrict__ xm, unsigned char* __restrict__ m1out)
{
    __shared__ float sp[18*131];
    __shared__ float smv[10*66];
    const int blk = blockIdx.x;          // 6144 = 768 bc x 8 row-tiles
    const int bc = blk >> 3;
    const int i0 = (blk & 7) * 16;
    const int c = bc % C_;
    const int t = threadIdx.x;
    const size_t pb = (size_t)bc * HW;
    const size_t mb = (size_t)bc * PLANE0;
    for (int q = t; q < 2340; q += 256) {
        int rr = q / 130, cc = q - rr*130;
        int gi = i0 + rr - 1, gj = cc - 1;
        float v = 0.f;
        if ((unsigned)gi < 128u && (unsigned)gj < 128u) v = pre[pb + gi*128 + gj];
        sp[rr*131 + cc] = v;
    }
    for (int q = t; q < 660; q += 256) {
        int rr = q / 66, cc = q - rr*66;
        int mi = (i0 >> 1) + rr - 1, mj = cc - 1;
        float v = 0.f;
        if ((unsigned)mi < 64u && (unsigned)mj < 64u) v = (float)mu[mb + mi*64 + mj];
        smv[rr*66 + cc] = v;
    }
    __syncthreads();
    float w9[9];
    #pragma unroll
    for (int k = 0; k < 9; ++k) w9[k] = wc[c*9 + k];
    const float bcc = bcast[c];
    const int rr = t >> 4, c8 = (t & 15) * 8;
    float ox[8]; unsigned mo = 0, mo2 = 0;
    #pragma unroll
    for (int u = 0; u < 8; ++u) {
        int j = c8 + u;
        float o = 0.f, s = 0.f;
        #pragma unroll
        for (int di = 0; di < 3; ++di) {
            int gi = i0 + rr + di - 1;
            int mrow = (gi >> 1) - (i0 >> 1) + 1;
            #pragma unroll
            for (int dj = 0; dj < 3; ++dj) {
                int gj = j + dj - 1;
                float m0v = smv[mrow*66 + (gj >> 1) + 1];
                s += m0v;
                o += m0v * sp[(rr+di)*131 + j + dj] * w9[di*3 + dj];
            }
        }
        bool valid = s > 0.f;
        ox[u] = valid ? (o * (9.f / s) + bcc) : 0.f;
        unsigned bit = valid ? 1u : 0u;
        if (u < 4) mo |= bit << (8*u); else mo2 |= bit << (8*(u-4));
    }
    size_t oidx = pb + (size_t)(i0 + rr)*128 + c8;
    f32x4 v0 = {ox[0], ox[1], ox[2], ox[3]};
    f32x4 v1 = {ox[4], ox[5], ox[6], ox[7]};
    *(f32x4*)&xm[oidx] = v0;
    *(f32x4*)&xm[oidx + 4] = v1;
    *(unsigned*)&m1out[oidx] = mo;
    *(unsigned*)&m1out[oidx + 4] = mo2;
}

// ---------------- K3: channel-sum of mask1 ----------------
__global__ __launch_bounds__(256) void k_rowsum(const unsigned char* __restrict__ m1,
                                                float* __restrict__ S)
{
    __shared__ float red[128];
    int bi = blockIdx.x;                // b*128 + i
    int b = bi >> 7, i = bi & 127;
    int t = threadIdx.x;
    int j = t & 127, half = t >> 7;
    float s = 0.f;
    size_t base = (size_t)b*C_*HW + (size_t)(half*96)*HW + (size_t)i*H_ + j;
    for (int c = 0; c < 96; ++c) s += (float)m1[base + (size_t)c*HW];
    if (half) red[j] = s;
    __syncthreads();
    if (!half) S[bi*H_ + j] = s + red[j];
}

// ---------------- K4: window-sum -> expand factor & mh ----------------
__global__ __launch_bounds__(256) void k_facm(const float* __restrict__ S,
                                              float* __restrict__ fac, float* __restrict__ mh)
{
    int px = blockIdx.x*256 + threadIdx.x;
    if (px >= NPIX) return;
    int j = px & 127, i = (px >> 7) & 127, b = px >> 14;
    float w3 = 0.f;
    #pragma unroll
    for (int di = -1; di <= 1; ++di) {
        int gi = i + di; if ((unsigned)gi >= (unsigned)H_) continue;
        #pragma unroll
        for (int dj = -1; dj <= 1; ++dj) {
            int gj = j + dj; if ((unsigned)gj >= (unsigned)H_) continue;
            w3 += S[(b*H_ + gi)*H_ + gj];
        }
    }
    bool v = w3 > 0.f;
    fac[px] = v ? 1728.f / w3 : 0.f;
    mh[px]  = v ? 1.f : 0.f;
}

// ---------------- K4b: weight convert + permute (K-major) ----------------
// web3: tile = p*54 + sc*9 + r, layout [c8 4][e 384][j 8]:
//   value = we[(p*384+e)*1728 + (sc*32 + c8*8 + j)*9 + r]
// wpb3: chunk = p*6 + h*3 + c3, layout [e8 8][co 192][8]; el = c3*64 + e8*8 + j;
//   e = p*384 + (el/48)*96 + h*48 + (el%48);  value = wp[co*768 + e]
// gb  : gamma bf16 [co][c]
__global__ __launch_bounds__(256) void k_wcvt(const float* __restrict__ we,
                                              const float* __restrict__ wp,
                                              const float* __restrict__ gamma,
                                              short* __restrict__ web3,
                                              short* __restrict__ wpb3,
                                              short* __restrict__ gb)
{
    int idx = blockIdx.x*256 + threadIdx.x;
    const int N1 = 108*12288;        // 1,327,104
    const int N2 = 12*12288;         // 147,456
    if (idx < N1) {
        int tile = idx / 12288, rem = idx % 12288;
        int g = rem >> 3, j = rem & 7;
        int c8 = g / 384, e = g % 384;
        int p = tile / 54, sc = (tile % 54) / 9, r = tile % 9;
        web3[idx] = (short)f2bf(we[(size_t)(p*384 + e)*1728 + (sc*32 + c8*8 + j)*9 + r]);
    } else if (idx < N1 + N2) {
        int i2 = idx - N1;
        int chunk = i2 / 12288, rem = i2 % 12288;
        int g = rem >> 3, j = rem & 7;
        int e8 = g / 192, co = g % 192;
        int p = chunk / 6, hf = (chunk % 6) / 3, c3 = chunk % 3;
        int el = c3*64 + e8*8 + j;
        int e = p*384 + (el/48)*96 + hf*48 + (el%48);
        wpb3[i2] = (short)f2bf(wp[(size_t)co*E_ + e]);
    } else {
        int i3 = idx - N1 - N2;
        if (i3 < C_*C_) gb[i3] = (short)f2bf(gamma[i3]);
    }
}

// ---------------- K4c: xm f32 [c][pix] -> xmT bf16 [b][130][130][192] (interior) ----------------
__global__ __launch_bounds__(256) void k_xmt(const float* __restrict__ xm,
                                             short* __restrict__ xmT)
{
    __shared__ float sm[64*65];
    const int gx = blockIdx.x;           // 3072 = 3 cb * 1024 pb
    const int cb = gx >> 10, pb = gx & 1023;
    const int c0 = cb*64, pix0 = pb*64;
    const int b = pix0 >> 14, pixb = pix0 & 16383;
    const int t = threadIdx.x;
    const int lane6 = t & 63, hi4 = t >> 6;
    #pragma unroll
    for (int it = 0; it < 16; ++it) {
        int r4 = it*4 + hi4;
        sm[r4*65 + lane6] = xm[((size_t)(b*C_ + c0 + r4))*HW + pixb + lane6];
    }
    __syncthreads();
    #pragma unroll
    for (int it = 0; it < 2; ++it) {
        int q = it*256 + t;
        int pp = q >> 3, c8 = q & 7;
        int p = pixb + pp;
        int i = p >> 7, j = p & 127;
        bf16x8 v;
        #pragma unroll
        for (int jj = 0; jj < 8; ++jj) v[jj] = (short)f2bf(sm[(c8*8+jj)*65 + pp]);
        *(bf16x8*)&xmT[((size_t)(b*XTPL + (i+1)*XTW + (j+1)))*192 + c0 + c8*8] = v;
    }
}

// ---------------- K5: MFMA fused MBConv — 74KB LDS, 2 blocks/CU, no acc/accy overlap ----------------
// Full silu right after expand: half0 -> hB, half1 packed into 24 u32 regs (acc dies first).
__global__ __launch_bounds__(512, 2) void k_mbconv(
    const short* __restrict__ xmT, const short* __restrict__ web3,
    const short* __restrict__ wpb3, const float* __restrict__ be,
    const float* __restrict__ bp, const float* __restrict__ bcast,
    const float* __restrict__ fac, const float* __restrict__ mh,
    const unsigned char* __restrict__ m1, float* __restrict__ xmy)
{
    __shared__ __align__(16) char smem[74112];
    // expand: apat @0 [c8 4][256 pos][8] 16,384 (pos>=180 junk) | bB @16,384 [2][12288sh] 49,152 -> 65,536
    // proj:   hB @0 [el8 24][stride 1032 sh] 49,536 | wpB @49,536 [12288sh] 24,576 -> 74,112
    // epi:    fbuf @0 [192][68] f32 52,224
    short* apat = (short*)smem;
    short* bB0  = (short*)(smem + 16384);
    short* bB1  = (short*)(smem + 16384 + 24576);
    short* hB   = (short*)smem;
    short* wpB  = (short*)(smem + 49536);
    float* fbuf = (float*)smem;

    // XCD-aware swizzle: 512 blocks = 8 XCDs x 64 contiguous
    const int blk = (blockIdx.x & 7)*64 + (blockIdx.x >> 3);
    const int b = blk >> 7;                       // 4b x 16ti x 8tj
    const int ti = (blk >> 3) & 15, tj = blk & 7;
    const int i0 = ti*8, j0 = tj*16;              // tile = 8 rows x 16 cols
    const int t = threadIdx.x;
    const int w = t >> 6, l = t & 63;
    const int wm2 = w >> 2, we2 = w & 3;
    const int m0 = wm2 * 64;
    const int lo = l & 15, hi = l >> 4;

#define ISSUE_A(sc_) do {                                                       \
    const int c0_ = (sc_)*32;                                                   \
    _Pragma("unroll")                                                           \
    for (int it_ = 0; it_ < 2; ++it_) {                                         \
        int q_ = it_*512 + t;                                                   \
        int c8_ = q_ >> 8, pos_ = q_ & 255;                                     \
        int rr_ = pos_/18, cc_ = pos_ - rr_*18;                                 \
        gll16(&xmT[((size_t)(b*XTPL + (i0+rr_)*XTW + (j0+cc_)))*192 + c0_       \
                   + c8_*8], &apat[q_*8]);                                      \
    }                                                                           \
} while(0)

#define ISSUE_B(tileIdx_, dst_) do {                                            \
    const size_t off_ = (size_t)(tileIdx_) * 12288;                             \
    _Pragma("unroll")                                                           \
    for (int it_ = 0; it_ < 3; ++it_) {                                         \
        int q_ = it_*512 + t;                                                   \
        gll16(&web3[off_ + q_*8], &(dst_)[q_*8]);                               \
    }                                                                           \
} while(0)

#define ISSUE_WP(chunkIdx_) do {                                                \
    const size_t off_ = (size_t)(chunkIdx_) * 12288;                            \
    _Pragma("unroll")                                                           \
    for (int it_ = 0; it_ < 3; ++it_) {                                         \
        int q_ = it_*512 + t;                                                   \
        gll16(&wpb3[off_ + q_*8], &wpB[q_*8]);                                  \
    }                                                                           \
} while(0)

#define WAITBAR(N_) do {                                                        \
    asm volatile("s_waitcnt vmcnt(" #N_ ") lgkmcnt(0)" ::: "memory");           \
    __builtin_amdgcn_s_barrier();                                               \
    __builtin_amdgcn_sched_barrier(0);                                          \
} while(0)

#define LGKMBAR() do {                                                          \
    asm volatile("s_waitcnt lgkmcnt(0)" ::: "memory");                          \
    __builtin_amdgcn_s_barrier();                                               \
    __builtin_amdgcn_sched_barrier(0);                                          \
} while(0)

    // per-thread invariant LDS bases (short indices)
    int aoffS[4], boffS[6], hpxS[4], wcoS[3];
    #pragma unroll
    for (int af = 0; af < 4; ++af) {
        int px = m0 + af*16 + lo;
        aoffS[af] = (hi*256 + (px >> 4)*18 + (px & 15)) * 8;
        hpxS[af]  = px * 8;
    }
    #pragma unroll
    for (int nf = 0; nf < 6; ++nf)
        boffS[nf] = (hi*384 + we2*96 + nf*16 + lo) * 8;
    #pragma unroll
    for (int nf = 0; nf < 3; ++nf)
        wcoS[nf] = (we2*48 + nf*16 + lo) * 8;
    const int hrowS = hi * 1032;
    const int wrowS = hi * 1536;

    // prologue
    ISSUE_B(0, bB0);

    #pragma unroll 1
    for (int p = 0; p < 2; ++p) {
        // ================= expand: 54 taps =================
        f32x4 acc[4][6];
        #pragma unroll
        for (int a = 0; a < 4; ++a)
            #pragma unroll
            for (int n = 0; n < 6; ++n) acc[a][n] = (f32x4){0.f,0.f,0.f,0.f};

        #pragma unroll 1
        for (int sc = 0; sc < 6; ++sc) {
            const int tbase = p*54 + sc*9;
            const int scp = sc & 1;
            #pragma unroll
            for (int r = 0; r < 9; ++r) {
                const int rv = (r/3)*18 + (r%3);            // compile-time
                short* bcur = ((scp ^ (r & 1)) ? bB1 : bB0);
                short* bnxt = ((scp ^ (r & 1)) ? bB0 : bB1);
                if (r == 0) {
                    WAITBAR(0);                 // B(tile) landed; apat reads done
                    ISSUE_A(sc);
                    ISSUE_B(tbase + 1, bnxt);
                    asm volatile("s_waitcnt vmcnt(3) lgkmcnt(0)" ::: "memory");
                    __builtin_amdgcn_s_barrier();
                    __builtin_amdgcn_sched_barrier(0);
                } else {
                    WAITBAR(0);                 // B(tile) landed; bnxt reads (r-2) done
                    if (!(sc == 5 && r == 8)) ISSUE_B(tbase + r + 1, bnxt);
                }
                bf16x8 a[4], bb[6];
                #pragma unroll
                for (int af = 0; af < 4; ++af)
                    a[af] = *(const bf16x8*)&apat[aoffS[af] + rv*8];
                #pragma unroll
                for (int nf = 0; nf < 6; ++nf)
                    bb[nf] = *(const bf16x8*)&bcur[boffS[nf]];
                __builtin_amdgcn_s_setprio(1);
                #pragma unroll
                for (int af = 0; af < 4; ++af)
                    #pragma unroll
                    for (int nf = 0; nf < 6; ++nf)
                        acc[af][nf] = __builtin_amdgcn_mfma_f32_16x16x32_bf16(
                            a[af], bb[nf], acc[af][nf], 0, 0, 0);
                __builtin_amdgcn_s_setprio(0);
            }
        }

        // ================= full silu (acc dies here) =================
        LGKMBAR();                         // tap-53 reads done; apat/bB dead; hB/wpB live
        ISSUE_WP(p*6);                     // h0 chunk0 -> wpB (disjoint from hB)
        unsigned hpk[24];                  // half1 packed bf16 pairs
        #pragma unroll
        for (int h2 = 0; h2 < 2; ++h2) {
            #pragma unroll
            for (int n3 = 0; n3 < 3; ++n3) {
                const int nf = h2*3 + n3;
                int el = we2*48 + n3*16 + lo;
                int e_glob = we2*96 + h2*48 + n3*16 + lo;
                float bev = be[p*384 + e_glob];
                int hb = (el >> 3)*1032 + (el & 7);
                #pragma unroll
                for (int af = 0; af < 4; ++af) {
                    float hv[4];
                    #pragma unroll
                    for (int reg = 0; reg < 4; ++reg) {
                        int px = m0 + af*16 + hi*4 + reg;
                        float fr = fac[b*HW + (i0 + (px >> 4))*128 + j0 + (px & 15)];
                        float v = acc[af][nf][reg]*fr + bev;
                        hv[reg] = (fr > 0.f) ? v / (1.f + __expf(-v)) : 0.f;
                    }
                    if (h2 == 0) {
                        #pragma unroll
                        for (int reg = 0; reg < 4; ++reg) {
                            int px = m0 + af*16 + hi*4 + reg;
                            hB[hb + px*8] = (short)f2bf(hv[reg]);
                        }
                    } else {
                        hpk[af*6 + n3*2 + 0] =
                            (unsigned)f2bf(hv[0]) | ((unsigned)f2bf(hv[1]) << 16);
                        hpk[af*6 + n3*2 + 1] =
                            (unsigned)f2bf(hv[2]) | ((unsigned)f2bf(hv[3]) << 16);
                    }
                }
            }
        }

        // ================= proj: 2 halves x 3 chunks of 64e =================
        f32x4 accy[4][3];
        #pragma unroll
        for (int a = 0; a < 4; ++a)
            #pragma unroll
            for (int n = 0; n < 3; ++n) accy[a][n] = (f32x4){0.f,0.f,0.f,0.f};

        #pragma unroll 1
        for (int h = 0; h < 2; ++h) {
            if (h == 1) {
                LGKMBAR();                 // h0 proj reads of hB done -> safe to overwrite
                #pragma unroll
                for (int n3 = 0; n3 < 3; ++n3) {
                    int el = we2*48 + n3*16 + lo;
                    int hb = (el >> 3)*1032 + (el & 7);
                    #pragma unroll
                    for (int af = 0; af < 4; ++af) {
                        int pxb = m0 + af*16 + hi*4;
                        unsigned p0 = hpk[af*6 + n3*2 + 0];
                        unsigned p1 = hpk[af*6 + n3*2 + 1];
                        hB[hb + pxb*8]     = (short)(p0 & 0xFFFFu);
                        hB[hb + (pxb+1)*8] = (short)(p0 >> 16);
                        hB[hb + (pxb+2)*8] = (short)(p1 & 0xFFFFu);
                        hB[hb + (pxb+3)*8] = (short)(p1 >> 16);
                    }
                }
            }
            #pragma unroll 1
            for (int c3 = 0; c3 < 3; ++c3) {
                if (c3 > 0) LGKMBAR();     // prev chunk reads done before wpB overwrite
                if (!(h == 0 && c3 == 0)) ISSUE_WP(p*6 + h*3 + c3);
                asm volatile("s_waitcnt vmcnt(0) lgkmcnt(0)" ::: "memory");
                __builtin_amdgcn_s_barrier();
                __builtin_amdgcn_sched_barrier(0);
                #pragma unroll
                for (int ks = 0; ks < 2; ++ks) {
                    bf16x8 a[4], bb[3];
                    #pragma unroll
                    for (int af = 0; af < 4; ++af)
                        a[af] = *(const bf16x8*)&hB[(c3*8 + ks*4)*1032 + hrowS + hpxS[af]];
                    #pragma unroll
                    for (int nf = 0; nf < 3; ++nf)
                        bb[nf] = *(const bf16x8*)&wpB[ks*4*1536 + wrowS + wcoS[nf]];
                    __builtin_amdgcn_s_setprio(1);
                    #pragma unroll
                    for (int af = 0; af < 4; ++af)
                        #pragma unroll
                        for (int nf = 0; nf < 3; ++nf)
                            accy[af][nf] = __builtin_amdgcn_mfma_f32_16x16x32_bf16(
                                a[af], bb[nf], accy[af][nf], 0, 0, 0);
                    __builtin_amdgcn_s_setprio(0);
                }
            }
        }

        // ================= per-pass y accumulate =================
        LGKMBAR();                         // last proj reads done; hB/wpB dead
        #pragma unroll 1
        for (int ph = 0; ph < 2; ++ph) {
            if (wm2 == ph) {
                #pragma unroll
                for (int af = 0; af < 4; ++af)
                    #pragma unroll
                    for (int nf = 0; nf < 3; ++nf) {
                        int co = we2*48 + nf*16 + lo;
                        int pxl = af*16 + hi*4;
                        *(f32x4*)&fbuf[co*68 + pxl] = accy[af][nf];
                    }
            }
            __syncthreads();
            #pragma unroll 1
            for (int it = 0; it < 6; ++it) {
                int q = it*512 + t;              // 3072 = 192co x 16 px-quads
                int co = q >> 4, px4 = (q & 15) << 2;
                int px = ph*64 + px4;
                int pi = px >> 4, pj = px & 15;
                size_t gidx = ((size_t)(b*C_ + co))*HW + (size_t)(i0+pi)*128 + j0 + pj;
                f32x4 pv = *(f32x4*)&fbuf[co*68 + px4];
                f32x4 prev = *(const f32x4*)&xmy[gidx];
                f32x4 o;
                if (p == 0) {
                    int pixg = b*HW + (i0+pi)*128 + j0 + pj;
                    f32x4 mh4 = *(const f32x4*)&mh[pixg];
                    unsigned mu4 = *(const unsigned*)&m1[gidx];
                    float bpc = bp[co], bcc = bcast[co];
                    #pragma unroll
                    for (int k = 0; k < 4; ++k)
                        o[k] = pv[k] + bpc + prev[k] + bcc*(mh4[k] - (float)((mu4 >> (8*k)) & 255u));
                } else {
                    #pragma unroll
                    for (int k = 0; k < 4; ++k) o[k] = prev[k] + pv[k];
                }
                *(f32x4*)&xmy[gidx] = o;
            }
            __syncthreads();
        }
        if (p == 0) ISSUE_B(54, bB0);      // after final sync: fbuf reads done
    }
#undef ISSUE_A
#undef ISSUE_B
#undef ISSUE_WP
#undef WAITBAR
#undef LGKMBAR
}

// ---------------- K6: MFMA GDN, 2x128 px tiles ----------------
__global__ __launch_bounds__(512, 2) void k_gdn(
    const short* __restrict__ gb, const float* __restrict__ beta,
    const float* __restrict__ mh, float* __restrict__ dout)
{
    __shared__ __align__(16) char smem[101376];
    short* aB = (short*)smem;               // [256][104] 53,248
    short* bG = (short*)(smem + 53248);     // [192][104] 39,936
    float* fbuf = (float*)smem;             // [192][132]
    const float* y = dout + NOUT;

    const int blk = blockIdx.x;             // 256 = 4b * 64 row-pairs
    const int b = blk >> 6;
    const int row0 = (blk & 63) * 2;
    const int t = threadIdx.x;
    const int w = t >> 6, l = t & 63;
    const int wm = w >> 1, we_ = w & 1;
    const int m0 = wm * 64;
    const int lo = l & 15, hi = l >> 4;

    f32x4 acc[4][6];
    #pragma unroll
    for (int a = 0; a < 4; ++a)
        #pragma unroll
        for (int n = 0; n < 6; ++n) acc[a][n] = (f32x4){0.f,0.f,0.f,0.f};

    #pragma unroll 1
    for (int ch = 0; ch < 2; ++ch) {
        __syncthreads();
        #pragma unroll 1
        for (int it = 0; it < 12; ++it) {
            int q = it*512 + t;                 // 6144 = 96c x 64 px-chunks
            int cL = q >> 6, px4 = (q & 63) << 2;
            int c = ch*96 + cL;
            int pi = px4 >> 7, pj = px4 & 127;
            f32x4 yv = *(const f32x4*)&y[((size_t)(b*C_ + c))*HW + (size_t)(row0+pi)*128 + pj];
            #pragma unroll
            for (int k = 0; k < 4; ++k)
                aB[(px4+k)*104 + cL] = (short)f2bf(yv[k]*yv[k]);
        }
        #pragma unroll 1
        for (int it = 0; it < 5; ++it) {
            int q = it*512 + t;
            if (q < 2304) {
                int co = q / 12, e8 = q - co*12;
                *(bf16x8*)&bG[co*104 + e8*8] = *(const bf16x8*)&gb[co*192 + ch*96 + e8*8];
            }
        }
        __syncthreads();
        #pragma unroll
        for (int ks = 0; ks < 3; ++ks) {
            const int koff = ks*32 + hi*8;
            bf16x8 a[4], bb[6];
            #pragma unroll
            for (int af = 0; af < 4; ++af)
                a[af] = *(const bf16x8*)&aB[(m0 + af*16 + lo)*104 + koff];
            #pragma unroll
            for (int nf = 0; nf < 6; ++nf)
                bb[nf] = *(const bf16x8*)&bG[(we_*96 + nf*16 + lo)*104 + koff];
            #pragma unroll
            for (int af = 0; af < 4; ++af)
                #pragma unroll
                for (int nf = 0; nf < 6; ++nf)
                    acc[af][nf] = __builtin_amdgcn_mfma_f32_16x16x32_bf16(
                        a[af], bb[nf], acc[af][nf], 0, 0, 0);
        }
    }

    #pragma unroll 1
    for (int ph = 0; ph < 2; ++ph) {
        __syncthreads();
        if ((wm >> 1) == ph) {
            #pragma unroll
            for (int af = 0; af < 4; ++af)
                #pragma unroll
                for (int nf = 0; nf < 6; ++nf) {
                    int co = we_*96 + nf*16 + lo;
                    int pxl = (wm&1)*64 + af*16 + hi*4;
                    *(f32x4*)&fbuf[co*132 + pxl] = acc[af][nf];
                }
        }
        __syncthreads();
        #pragma unroll 1
        for (int it = 0; it < 12; ++it) {
            int q = it*512 + t;
            int co = q >> 5, px4 = (q & 31) << 2;
            size_t gidx = ((size_t)(b*C_ + co))*HW + (size_t)(row0+ph)*128 + px4;
            int pixg = b*HW + (row0+ph)*128 + px4;
            f32x4 nv = *(f32x4*)&fbuf[co*132 + px4];
            f32x4 yv = *(const f32x4*)&y[gidx];
            f32x4 mh4 = *(const f32x4*)&mh[pixg];
            float bt = beta[co];
            f32x4 o;
            #pragma unroll
            for (int k = 0; k < 4; ++k)
                o[k] = (mh4[k] > 0.f) ? yv[k]*rsqrtf(bt + nv[k]) : 0.f;
            *(f32x4*)&dout[gidx] = o;
            *(f32x4*)&dout[(size_t)NOUT + gidx] = mh4;   // final mask (y read above)
        }
    }
}

extern "C" void kernel_launch(void* const* d_in, const int* in_sizes, int n_in,
                              void* d_out, int out_size, void* d_ws, size_t ws_size,
                              hipStream_t stream)
{
    const float* ll = (const float*)d_in[0];
    const float* b1 = (const float*)d_in[1];
    const float* b2 = (const float*)d_in[2];
    const float* b3 = (const float*)d_in[3];
    const int* llm = (const int*)d_in[4];
    const int* m1i = (const int*)d_in[5];
    const int* m2i = (const int*)d_in[6];
    const int* m3i = (const int*)d_in[7];
    const float* wc    = (const float*)d_in[8];
    const float* bcast = (const float*)d_in[9];
    const float* we    = (const float*)d_in[10];
    const float* be    = (const float*)d_in[11];
    const float* wp    = (const float*)d_in[12];
    const float* bp    = (const float*)d_in[13];
    const float* gamma = (const float*)d_in[14];
    const float* beta  = (const float*)d_in[15];

    char* ws = (char*)d_ws;
    float* S   = (float*)(ws + OFF_S);
    float* fac = (float*)(ws + OFF_FAC);
    float* mh  = (float*)(ws + OFF_MH);
    unsigned char* mu  = (unsigned char*)(ws + OFF_MU);
    unsigned char* m1b = (unsigned char*)(ws + OFF_M1);
    short* web3 = (short*)(ws + OFF_WEB3);
    short* wpb3 = (short*)(ws + OFF_WPB3);
    short* gb   = (short*)(ws + OFF_GB);

    float* outF = (float*)d_out;
    float* pre = outF;              // [0:NOUT] pre -> xmT halo -> final out
    float* xm  = outF + NOUT;       // [NOUT:2NOUT] xm -> y (in-place) -> final mask
    short* xmT = (short*)d_out;

    k_wcvt<<<dim3(5904), dim3(256), 0, stream>>>(we, wp, gamma, web3, wpb3, gb);
    k_idwt<<<dim3(B_*C_), dim3(512), 0, stream>>>(ll, b1, b2, b3, llm, m1i, m2i, m3i, pre, mu);
    k_cast<<<dim3(6144), dim3(256), 0, stream>>>(pre, mu, wc, bcast, xm, m1b);
    k_zhalo<<<dim3(194), dim3(256), 0, stream>>>(xmT);
    k_xmt<<<dim3(3072), dim3(256), 0, stream>>>(xm, xmT);
    k_rowsum<<<dim3(B_*H_), dim3(256), 0, stream>>>(m1b, S);
    k_facm<<<dim3(NPIX/256), dim3(256), 0, stream>>>(S, fac, mh);
    k_mbconv<<<dim3(512), dim3(512), 0, stream>>>(xmT, web3, wpb3, be, bp, bcast, fac, mh, m1b, xm);
    k_gdn<<<dim3(256), dim3(512), 0, stream>>>(gb, beta, mh, outF);
}